// Round 1
// baseline (1106.544 us; speedup 1.0000x reference)
//
#include <hip/hip_runtime.h>

// ---------------------------------------------------------------------------
// GAMLNET GNN forward: 3x GIN (sum-agg) -> linear -> concat -> SAGE(mean) x2
// N=50000 nodes, E=800000 edges, F=64, GIN_F=32, H1=128, H2=256, OUT=2
// Strategy: build CSR (by dst) once per launch, gather-based aggregation,
// tiled fp32 GEMM (64x128 block tile, 8x4 per thread), fused bias/relu/add.
// ---------------------------------------------------------------------------

#define FLAG_BIAS 1
#define FLAG_ADD  2
#define FLAG_RELU 4

// --- edge dtype detection: if input is int64, odd int32 words are all zero ---
__global__ void detect_kernel(const int* __restrict__ ei, int ncheck, int* flag) {
    int t = blockIdx.x * blockDim.x + threadIdx.x;
    if (t < ncheck) {
        if (ei[2 * t + 1] != 0) atomicAnd(flag, 0);   // nonzero odd word -> int32 layout
    }
}

__global__ void convert_kernel(const int* __restrict__ ei, int E, const int* __restrict__ flag,
                               int* __restrict__ src, int* __restrict__ dst) {
    int e = blockIdx.x * blockDim.x + threadIdx.x;
    if (e >= E) return;
    if (*flag) {  // int64 layout: value in low word
        src[e] = ei[2 * (size_t)e];
        dst[e] = ei[2 * ((size_t)E + e)];
    } else {      // int32 layout
        src[e] = ei[e];
        dst[e] = ei[(size_t)E + e];
    }
}

__global__ void deg_kernel(const int* __restrict__ dst, int E, int* __restrict__ deg) {
    int e = blockIdx.x * blockDim.x + threadIdx.x;
    if (e < E) atomicAdd(&deg[dst[e]], 1);
}

// single-block exclusive scan over deg[0..n) -> rowptr[0..n], also init cursor
__global__ void scan_kernel(const int* __restrict__ deg, int n,
                            int* __restrict__ rowptr, int* __restrict__ cursor) {
    __shared__ int sh[1024];
    __shared__ int carry;
    if (threadIdx.x == 0) carry = 0;
    __syncthreads();
    for (int base = 0; base < n; base += 1024) {
        int i = base + (int)threadIdx.x;
        int v = (i < n) ? deg[i] : 0;
        sh[threadIdx.x] = v;
        __syncthreads();
        for (int off = 1; off < 1024; off <<= 1) {
            int t = 0;
            if ((int)threadIdx.x >= off) t = sh[threadIdx.x - off];
            __syncthreads();
            sh[threadIdx.x] += t;
            __syncthreads();
        }
        int incl = sh[threadIdx.x];
        int c0 = carry;
        int excl = c0 + incl - v;
        if (i < n) { rowptr[i] = excl; cursor[i] = excl; }
        __syncthreads();
        if (threadIdx.x == 1023) carry = c0 + sh[1023];
        __syncthreads();
    }
    if (threadIdx.x == 0) rowptr[n] = carry;
}

__global__ void invdeg_kernel(const int* __restrict__ deg, int n, float* __restrict__ invdeg) {
    int i = blockIdx.x * blockDim.x + threadIdx.x;
    if (i < n) invdeg[i] = 1.0f / fmaxf((float)deg[i], 1.0f);
}

__global__ void scatter_kernel(const int* __restrict__ src, const int* __restrict__ dst, int E,
                               int* __restrict__ cursor, int* __restrict__ col) {
    int e = blockIdx.x * blockDim.x + threadIdx.x;
    if (e < E) {
        int p = atomicAdd(&cursor[dst[e]], 1);
        col[p] = src[e];
    }
}

// h0 = x[:, :32]
__global__ void slice_kernel(const float* __restrict__ x, float* __restrict__ h, int total) {
    int idx = blockIdx.x * blockDim.x + threadIdx.x;
    if (idx < total) {
        int i = idx >> 5, c = idx & 31;
        h[idx] = x[(size_t)i * 64 + c];
    }
}

// MODE 0: out[i] = h[i] + sum_{j in nbr(i)} h[j]   (GIN)
// MODE 1: out[i] = inv_deg[i] * sum_{j} h[j]       (mean)
// blockDim.x == C (feature width); one block per node
template <int MODE>
__global__ void agg_kernel(const float* __restrict__ h, const int* __restrict__ rowptr,
                           const int* __restrict__ col, const float* __restrict__ invdeg,
                           float* __restrict__ out) {
    int i = blockIdx.x;
    int c = threadIdx.x;
    int C = blockDim.x;
    int p0 = rowptr[i], p1 = rowptr[i + 1];
    float s = 0.f;
    for (int p = p0; p < p1; ++p) {
        int j = col[p];
        s += h[(size_t)j * C + c];
    }
    if (MODE == 0) out[(size_t)i * C + c] = h[(size_t)i * C + c] + s;
    else           out[(size_t)i * C + c] = s * invdeg[i];
}

// hcat = [x (64) | g (128)] -> 192 wide
__global__ void concat_kernel(const float* __restrict__ x, const float* __restrict__ g,
                              float* __restrict__ hcat, int total) {
    int idx = blockIdx.x * blockDim.x + threadIdx.x;
    if (idx >= total) return;
    int i = idx / 192, c = idx % 192;
    hcat[idx] = (c < 64) ? x[(size_t)i * 64 + c] : g[(size_t)i * 128 + (c - 64)];
}

// C[M,Nc] = act(A[M,K] @ W[K,Nc] (+bias) (+existing C))
// tile: 64 rows x 128 cols, K-chunks of 32. 256 threads, 8 rows x 4 cols each.
#define BM 64
#define BN 128
#define KC 32
__global__ __launch_bounds__(256) void gemm_kernel(
    const float* __restrict__ A, const float* __restrict__ W,
    const float* __restrict__ bias, float* __restrict__ Cout,
    int M, int K, int Nc, int flags) {
    __shared__ float Ash[BM][KC + 1];
    __shared__ float Wsh[KC][BN];
    int rowbase = blockIdx.x * BM;
    int colbase = blockIdx.y * BN;
    int tid = threadIdx.x;
    int tr = tid >> 5;   // 0..7 -> rows tr*8 .. tr*8+7
    int tc = tid & 31;   // 0..31 -> cols tc*4 .. tc*4+3
    float acc[8][4];
#pragma unroll
    for (int i = 0; i < 8; ++i)
#pragma unroll
        for (int j = 0; j < 4; ++j) acc[i][j] = 0.f;

    for (int ko = 0; ko < K; ko += KC) {
        // A tile: 64x32 = 2048 floats, 2 float4 per thread
#pragma unroll
        for (int s = 0; s < 2; ++s) {
            int slot = tid + 256 * s;      // 0..511
            int r = slot >> 3;             // 8 float4 per row
            int f = slot & 7;
            int grow = rowbase + r;
            float4 v = make_float4(0.f, 0.f, 0.f, 0.f);
            if (grow < M) v = *(const float4*)&A[(size_t)grow * K + ko + 4 * f];
            Ash[r][4 * f + 0] = v.x;
            Ash[r][4 * f + 1] = v.y;
            Ash[r][4 * f + 2] = v.z;
            Ash[r][4 * f + 3] = v.w;
        }
        // W tile: 32x128 = 4096 floats, 4 float4 per thread
#pragma unroll
        for (int s = 0; s < 4; ++s) {
            int slot = tid + 256 * s;      // 0..1023
            int r = slot >> 5;             // 32 float4 per row
            int f = slot & 31;
            float4 v = *(const float4*)&W[(size_t)(ko + r) * Nc + colbase + 4 * f];
            *(float4*)&Wsh[r][4 * f] = v;
        }
        __syncthreads();
#pragma unroll
        for (int kk = 0; kk < KC; ++kk) {
            float a[8], w[4];
#pragma unroll
            for (int i = 0; i < 8; ++i) a[i] = Ash[tr * 8 + i][kk];
            float4 wv = *(const float4*)&Wsh[kk][tc * 4];
            w[0] = wv.x; w[1] = wv.y; w[2] = wv.z; w[3] = wv.w;
#pragma unroll
            for (int i = 0; i < 8; ++i)
#pragma unroll
                for (int j = 0; j < 4; ++j) acc[i][j] += a[i] * w[j];
        }
        __syncthreads();
    }

    int gcol = colbase + tc * 4;
    float4 bv = make_float4(0.f, 0.f, 0.f, 0.f);
    if (flags & FLAG_BIAS) bv = *(const float4*)&bias[gcol];
#pragma unroll
    for (int i = 0; i < 8; ++i) {
        int grow = rowbase + tr * 8 + i;
        if (grow >= M) continue;
        float4 v = make_float4(acc[i][0] + bv.x, acc[i][1] + bv.y,
                               acc[i][2] + bv.z, acc[i][3] + bv.w);
        float* cptr = &Cout[(size_t)grow * Nc + gcol];
        if (flags & FLAG_ADD) {
            float4 prev = *(const float4*)cptr;
            v.x += prev.x; v.y += prev.y; v.z += prev.z; v.w += prev.w;
        }
        if (flags & FLAG_RELU) {
            v.x = fmaxf(v.x, 0.f); v.y = fmaxf(v.y, 0.f);
            v.z = fmaxf(v.z, 0.f); v.w = fmaxf(v.w, 0.f);
        }
        *(float4*)cptr = v;
    }
}

// out[i,0:2] = h[i] @ wl + m2[i] @ wr + b ; one wave per node
__global__ void final_kernel(const float* __restrict__ h, const float* __restrict__ m2,
                             const float* __restrict__ wl, const float* __restrict__ wr,
                             const float* __restrict__ b, float* __restrict__ out, int M) {
    int wave = threadIdx.x >> 6;
    int lane = threadIdx.x & 63;
    int i = blockIdx.x * 4 + wave;
    if (i >= M) return;
    float p0 = 0.f, p1 = 0.f;
    for (int k = lane; k < 256; k += 64) {
        float hv = h[(size_t)i * 256 + k];
        float mv = m2[(size_t)i * 256 + k];
        p0 += hv * wl[2 * k]     + mv * wr[2 * k];
        p1 += hv * wl[2 * k + 1] + mv * wr[2 * k + 1];
    }
#pragma unroll
    for (int off = 32; off > 0; off >>= 1) {
        p0 += __shfl_down(p0, off);
        p1 += __shfl_down(p1, off);
    }
    if (lane == 0) {
        out[(size_t)i * 2 + 0] = p0 + b[0];
        out[(size_t)i * 2 + 1] = p1 + b[1];
    }
}

extern "C" void kernel_launch(void* const* d_in, const int* in_sizes, int n_in,
                              void* d_out, int out_size, void* d_ws, size_t ws_size,
                              hipStream_t stream) {
    const float* x      = (const float*)d_in[0];
    const int*   ei     = (const int*)d_in[1];
    const float* g_w1[3] = {(const float*)d_in[2], (const float*)d_in[6],  (const float*)d_in[10]};
    const float* g_b1[3] = {(const float*)d_in[3], (const float*)d_in[7],  (const float*)d_in[11]};
    const float* g_w2[3] = {(const float*)d_in[4], (const float*)d_in[8],  (const float*)d_in[12]};
    const float* g_b2[3] = {(const float*)d_in[5], (const float*)d_in[9],  (const float*)d_in[13]};
    const float* gout_w = (const float*)d_in[14];
    const float* gout_b = (const float*)d_in[15];
    const float* s0_wl  = (const float*)d_in[16];
    const float* s0_wr  = (const float*)d_in[17];
    const float* s0_b   = (const float*)d_in[18];
    const float* s1_wl  = (const float*)d_in[19];
    const float* s1_wr  = (const float*)d_in[20];
    const float* s1_b   = (const float*)d_in[21];
    float* out = (float*)d_out;

    const int N = in_sizes[0] / 64;
    const int E = in_sizes[1] / 2;

    char* ws = (char*)d_ws;
    size_t o = 0;
    auto take = [&](size_t bytes) -> char* {
        char* p = ws + o;
        o = (o + bytes + 255) & ~(size_t)255;
        return p;
    };
    float* bufA   = (float*)take((size_t)N * 256 * 4);
    float* bufB   = (float*)take((size_t)N * 256 * 4);
    float* bufC   = (float*)take((size_t)N * 256 * 4);
    int*   srcI   = (int*)take((size_t)E * 4);
    int*   dstI   = (int*)take((size_t)E * 4);
    int*   colI   = (int*)take((size_t)E * 4);
    int*   rowptr = (int*)take((size_t)(N + 1) * 4);
    int*   cursor = (int*)take((size_t)N * 4);
    int*   deg    = (int*)take((size_t)N * 4);
    float* invdeg = (float*)take((size_t)N * 4);
    int*   flag   = (int*)take(4);

    hipMemsetAsync(deg, 0, (size_t)N * 4, stream);
    hipMemsetAsync(flag, 1, 4, stream);   // 0x01010101 != 0 -> "assume int64"

    const int TB = 256;
    // --- graph preprocessing: CSR by dst ---
    detect_kernel<<<4, TB, 0, stream>>>(ei, 1024, flag);
    convert_kernel<<<(E + TB - 1) / TB, TB, 0, stream>>>(ei, E, flag, srcI, dstI);
    deg_kernel<<<(E + TB - 1) / TB, TB, 0, stream>>>(dstI, E, deg);
    scan_kernel<<<1, 1024, 0, stream>>>(deg, N, rowptr, cursor);
    invdeg_kernel<<<(N + TB - 1) / TB, TB, 0, stream>>>(deg, N, invdeg);
    scatter_kernel<<<(E + TB - 1) / TB, TB, 0, stream>>>(srcI, dstI, E, cursor, colI);

    auto gemm = [&](const float* A, const float* W, const float* bias, float* C,
                    int M, int K, int Nc, int flags) {
        dim3 grid((M + BM - 1) / BM, Nc / BN);
        gemm_kernel<<<grid, 256, 0, stream>>>(A, W, bias, C, M, K, Nc, flags);
    };

    // h0 = x[:, :32]
    slice_kernel<<<((N * 32) + TB - 1) / TB, TB, 0, stream>>>(x, bufA, N * 32);

    // --- GIN layer 0 (C=32 -> 128) ---
    agg_kernel<0><<<N, 32, 0, stream>>>(bufA, rowptr, colI, invdeg, bufB);
    gemm(bufB, g_w1[0], g_b1[0], bufC, N, 32, 128, FLAG_BIAS | FLAG_RELU);
    gemm(bufC, g_w2[0], g_b2[0], bufA, N, 128, 128, FLAG_BIAS | FLAG_RELU);

    // --- GIN layers 1,2 (C=128) ---
    for (int l = 1; l < 3; ++l) {
        agg_kernel<0><<<N, 128, 0, stream>>>(bufA, rowptr, colI, invdeg, bufB);
        gemm(bufB, g_w1[l], g_b1[l], bufC, N, 128, 128, FLAG_BIAS | FLAG_RELU);
        gemm(bufC, g_w2[l], g_b2[l], bufA, N, 128, 128, FLAG_BIAS | FLAG_RELU);
    }

    // gin_out = h @ gout_w + gout_b
    gemm(bufA, gout_w, gout_b, bufB, N, 128, 128, FLAG_BIAS);

    // hcat = [x | gin_out] (192 wide)
    concat_kernel<<<((N * 192) + TB - 1) / TB, TB, 0, stream>>>(x, bufB, bufC, N * 192);

    // mean1 = agg(hcat) * inv_deg
    agg_kernel<1><<<N, 192, 0, stream>>>(bufC, rowptr, colI, invdeg, bufB);

    // s0: relu(hcat @ wl + mean1 @ wr + b) -> 256 wide
    gemm(bufC, s0_wl, s0_b, bufA, N, 192, 256, FLAG_BIAS);
    gemm(bufB, s0_wr, nullptr, bufA, N, 192, 256, FLAG_ADD | FLAG_RELU);

    // mean2 = agg(h) * inv_deg (256 wide)
    agg_kernel<1><<<N, 256, 0, stream>>>(bufA, rowptr, colI, invdeg, bufB);

    // out = h @ s1_wl + mean2 @ s1_wr + b
    final_kernel<<<(N + 3) / 4, 256, 0, stream>>>(bufA, bufB, s1_wl, s1_wr, s1_b, out, N);
}

// Round 2
// 947.262 us; speedup vs baseline: 1.1682x; 1.1682x over previous
//
#include <hip/hip_runtime.h>

// ---------------------------------------------------------------------------
// GAMLNET GNN forward: 3x GIN (sum-agg) -> linear -> concat -> SAGE(mean) x2
// N=50000, E=800000, F=64, GIN_F=32, H1=128, H2=256, OUT=2
// R1: wave-per-node vectorized agg with x4 unrolled gather (MLP), 128x128
// fp32 GEMM with 8x8 micro-tiles and LDS-transposed A.
// ---------------------------------------------------------------------------

#define FLAG_BIAS 1
#define FLAG_ADD  2
#define FLAG_RELU 4

// --- edge dtype detection: if input is int64, odd int32 words are all zero ---
__global__ void detect_kernel(const int* __restrict__ ei, int ncheck, int* flag) {
    int t = blockIdx.x * blockDim.x + threadIdx.x;
    if (t < ncheck) {
        if (ei[2 * t + 1] != 0) atomicAnd(flag, 0);   // nonzero odd word -> int32 layout
    }
}

__global__ void convert_kernel(const int* __restrict__ ei, int E, const int* __restrict__ flag,
                               int* __restrict__ src, int* __restrict__ dst) {
    int e = blockIdx.x * blockDim.x + threadIdx.x;
    if (e >= E) return;
    if (*flag) {  // int64 layout: value in low word
        src[e] = ei[2 * (size_t)e];
        dst[e] = ei[2 * ((size_t)E + e)];
    } else {      // int32 layout
        src[e] = ei[e];
        dst[e] = ei[(size_t)E + e];
    }
}

__global__ void deg_kernel(const int* __restrict__ dst, int E, int* __restrict__ deg) {
    int e = blockIdx.x * blockDim.x + threadIdx.x;
    if (e < E) atomicAdd(&deg[dst[e]], 1);
}

// single-block exclusive scan over deg[0..n) -> rowptr[0..n], also init cursor
__global__ void scan_kernel(const int* __restrict__ deg, int n,
                            int* __restrict__ rowptr, int* __restrict__ cursor) {
    __shared__ int sh[1024];
    __shared__ int carry;
    if (threadIdx.x == 0) carry = 0;
    __syncthreads();
    for (int base = 0; base < n; base += 1024) {
        int i = base + (int)threadIdx.x;
        int v = (i < n) ? deg[i] : 0;
        sh[threadIdx.x] = v;
        __syncthreads();
        for (int off = 1; off < 1024; off <<= 1) {
            int t = 0;
            if ((int)threadIdx.x >= off) t = sh[threadIdx.x - off];
            __syncthreads();
            sh[threadIdx.x] += t;
            __syncthreads();
        }
        int incl = sh[threadIdx.x];
        int c0 = carry;
        int excl = c0 + incl - v;
        if (i < n) { rowptr[i] = excl; cursor[i] = excl; }
        __syncthreads();
        if (threadIdx.x == 1023) carry = c0 + sh[1023];
        __syncthreads();
    }
    if (threadIdx.x == 0) rowptr[n] = carry;
}

__global__ void invdeg_kernel(const int* __restrict__ deg, int n, float* __restrict__ invdeg) {
    int i = blockIdx.x * blockDim.x + threadIdx.x;
    if (i < n) invdeg[i] = 1.0f / fmaxf((float)deg[i], 1.0f);
}

__global__ void scatter_kernel(const int* __restrict__ src, const int* __restrict__ dst, int E,
                               int* __restrict__ cursor, int* __restrict__ col) {
    int e = blockIdx.x * blockDim.x + threadIdx.x;
    if (e < E) {
        int p = atomicAdd(&cursor[dst[e]], 1);
        col[p] = src[e];
    }
}

// h0 = x[:, :32]
__global__ void slice_kernel(const float* __restrict__ x, float* __restrict__ h, int total) {
    int idx = blockIdx.x * blockDim.x + threadIdx.x;
    if (idx < total) {
        int i = idx >> 5, c = idx & 31;
        h[idx] = x[(size_t)i * 64 + c];
    }
}

// hcat = [x (64) | g (128)] -> 192 wide
__global__ void concat_kernel(const float* __restrict__ x, const float* __restrict__ g,
                              float* __restrict__ hcat, int total) {
    int idx = blockIdx.x * blockDim.x + threadIdx.x;
    if (idx >= total) return;
    int i = idx / 192, c = idx % 192;
    hcat[idx] = (c < 64) ? x[(size_t)i * 64 + c] : g[(size_t)i * 128 + (c - 64)];
}

// ---------------------------------------------------------------------------
// Aggregation: one wave per node. lane handles VEC contiguous floats.
// MODE 0: out[i] = h[i] + sum_{j in nbr(i)} h[j]   (GIN)
// MODE 1: out[i] = inv_deg[i] * sum_{j} h[j]       (mean)
// Neighbor loop unrolled x4 with independent loads for MLP.
// ---------------------------------------------------------------------------
template <int C, int VEC, int MODE>
__global__ __launch_bounds__(256) void agg2_kernel(
    const float* __restrict__ h, int ldh,
    const int* __restrict__ rowptr, const int* __restrict__ col,
    const float* __restrict__ invdeg,
    float* __restrict__ out, int ldo, int Nn) {
    constexpr int LANES = C / VEC;
    int wid = blockIdx.x * 4 + ((int)threadIdx.x >> 6);
    int lane = (int)threadIdx.x & 63;
    if (wid >= Nn || lane >= LANES) return;

    const float* hb = h + (size_t)lane * VEC;
    float a0 = 0.f, a1 = 0.f, a2 = 0.f, a3 = 0.f;

    int p0 = rowptr[wid], p1 = rowptr[wid + 1];
    int p = p0;
    for (; p + 4 <= p1; p += 4) {
        int j0 = col[p], j1 = col[p + 1], j2 = col[p + 2], j3 = col[p + 3];
        if constexpr (VEC == 4) {
            float4 v0 = *(const float4*)(hb + (size_t)j0 * ldh);
            float4 v1 = *(const float4*)(hb + (size_t)j1 * ldh);
            float4 v2 = *(const float4*)(hb + (size_t)j2 * ldh);
            float4 v3 = *(const float4*)(hb + (size_t)j3 * ldh);
            a0 += v0.x + v1.x + v2.x + v3.x;
            a1 += v0.y + v1.y + v2.y + v3.y;
            a2 += v0.z + v1.z + v2.z + v3.z;
            a3 += v0.w + v1.w + v2.w + v3.w;
        } else if constexpr (VEC == 2) {
            float2 v0 = *(const float2*)(hb + (size_t)j0 * ldh);
            float2 v1 = *(const float2*)(hb + (size_t)j1 * ldh);
            float2 v2 = *(const float2*)(hb + (size_t)j2 * ldh);
            float2 v3 = *(const float2*)(hb + (size_t)j3 * ldh);
            a0 += v0.x + v1.x + v2.x + v3.x;
            a1 += v0.y + v1.y + v2.y + v3.y;
        } else {
            float v0 = hb[(size_t)j0 * ldh];
            float v1 = hb[(size_t)j1 * ldh];
            float v2 = hb[(size_t)j2 * ldh];
            float v3 = hb[(size_t)j3 * ldh];
            a0 += v0 + v1 + v2 + v3;
        }
    }
    for (; p < p1; ++p) {
        int j = col[p];
        if constexpr (VEC == 4) {
            float4 v = *(const float4*)(hb + (size_t)j * ldh);
            a0 += v.x; a1 += v.y; a2 += v.z; a3 += v.w;
        } else if constexpr (VEC == 2) {
            float2 v = *(const float2*)(hb + (size_t)j * ldh);
            a0 += v.x; a1 += v.y;
        } else {
            a0 += hb[(size_t)j * ldh];
        }
    }

    if constexpr (MODE == 0) {
        if constexpr (VEC == 4) {
            float4 v = *(const float4*)(hb + (size_t)wid * ldh);
            a0 += v.x; a1 += v.y; a2 += v.z; a3 += v.w;
        } else if constexpr (VEC == 2) {
            float2 v = *(const float2*)(hb + (size_t)wid * ldh);
            a0 += v.x; a1 += v.y;
        } else {
            a0 += hb[(size_t)wid * ldh];
        }
    } else {
        float s = invdeg[wid];
        a0 *= s; a1 *= s; a2 *= s; a3 *= s;
    }

    float* op = out + (size_t)wid * ldo + (size_t)lane * VEC;
    if constexpr (VEC == 4)      *(float4*)op = make_float4(a0, a1, a2, a3);
    else if constexpr (VEC == 2) *(float2*)op = make_float2(a0, a1);
    else                         *op = a0;
}

// ---------------------------------------------------------------------------
// fp32 GEMM: C[M,Nc] = act(A[M,K](lda) @ W[K,Nc] (+bias) (+existing C))
// 128x128 block tile, 256 threads, 8x8 micro-tile per thread, K-chunks of 16.
// A staged transposed in LDS (row pad 132 floats keeps float4 alignment and
// spreads banks); all fragment reads are ds_read_b128.
// ---------------------------------------------------------------------------
#define GBM 128
#define GBN 128
#define GKC 16
__global__ __launch_bounds__(256) void gemm2_kernel(
    const float* __restrict__ A, int lda,
    const float* __restrict__ W, int Nc,
    const float* __restrict__ bias, float* __restrict__ Cout,
    int M, int K, int flags) {
    __shared__ float AshT[GKC][GBM + 4];   // [k][row], row pad 4
    __shared__ float Wsh[GKC][GBN];        // [k][col]

    int rowbase = blockIdx.x * GBM;
    int colbase = blockIdx.y * GBN;
    int tid = threadIdx.x;
    int ty = tid >> 4;    // 0..15 -> rows ty*8..
    int tx = tid & 15;    // 0..15 -> cols tx*8..

    float acc[8][8];
#pragma unroll
    for (int i = 0; i < 8; ++i)
#pragma unroll
        for (int j = 0; j < 8; ++j) acc[i][j] = 0.f;

    for (int ko = 0; ko < K; ko += GKC) {
        // stage A: 128 rows x 16 k = 512 float4 (transposed into LDS)
#pragma unroll
        for (int s = 0; s < 2; ++s) {
            int idx = tid + 256 * s;          // 0..511
            int row = idx >> 2;               // 0..127
            int kf = idx & 3;                 // float4 index along K
            int grow = rowbase + row;
            float4 v = make_float4(0.f, 0.f, 0.f, 0.f);
            if (grow < M) v = *(const float4*)&A[(size_t)grow * lda + ko + kf * 4];
            AshT[kf * 4 + 0][row] = v.x;
            AshT[kf * 4 + 1][row] = v.y;
            AshT[kf * 4 + 2][row] = v.z;
            AshT[kf * 4 + 3][row] = v.w;
        }
        // stage W: 16 k x 128 cols = 512 float4
#pragma unroll
        for (int s = 0; s < 2; ++s) {
            int idx = tid + 256 * s;          // 0..511
            int kk = idx >> 5;                // 0..15
            int cf = idx & 31;                // 0..31
            float4 v = *(const float4*)&W[(size_t)(ko + kk) * Nc + colbase + cf * 4];
            *(float4*)&Wsh[kk][cf * 4] = v;
        }
        __syncthreads();
#pragma unroll
        for (int kk = 0; kk < GKC; ++kk) {
            float4 A0 = *(const float4*)&AshT[kk][ty * 8];
            float4 A1 = *(const float4*)&AshT[kk][ty * 8 + 4];
            float4 W0 = *(const float4*)&Wsh[kk][tx * 8];
            float4 W1 = *(const float4*)&Wsh[kk][tx * 8 + 4];
            float av[8] = {A0.x, A0.y, A0.z, A0.w, A1.x, A1.y, A1.z, A1.w};
            float wv[8] = {W0.x, W0.y, W0.z, W0.w, W1.x, W1.y, W1.z, W1.w};
#pragma unroll
            for (int i = 0; i < 8; ++i)
#pragma unroll
                for (int j = 0; j < 8; ++j) acc[i][j] += av[i] * wv[j];
        }
        __syncthreads();
    }

    int gcol = colbase + tx * 8;
    float4 bv0 = make_float4(0.f, 0.f, 0.f, 0.f), bv1 = bv0;
    if (flags & FLAG_BIAS) {
        bv0 = *(const float4*)&bias[gcol];
        bv1 = *(const float4*)&bias[gcol + 4];
    }
#pragma unroll
    for (int i = 0; i < 8; ++i) {
        int grow = rowbase + ty * 8 + i;
        if (grow >= M) continue;
        float* cptr = &Cout[(size_t)grow * Nc + gcol];
        float4 v0 = make_float4(acc[i][0] + bv0.x, acc[i][1] + bv0.y,
                                acc[i][2] + bv0.z, acc[i][3] + bv0.w);
        float4 v1 = make_float4(acc[i][4] + bv1.x, acc[i][5] + bv1.y,
                                acc[i][6] + bv1.z, acc[i][7] + bv1.w);
        if (flags & FLAG_ADD) {
            float4 p0 = *(const float4*)cptr;
            float4 p1 = *(const float4*)(cptr + 4);
            v0.x += p0.x; v0.y += p0.y; v0.z += p0.z; v0.w += p0.w;
            v1.x += p1.x; v1.y += p1.y; v1.z += p1.z; v1.w += p1.w;
        }
        if (flags & FLAG_RELU) {
            v0.x = fmaxf(v0.x, 0.f); v0.y = fmaxf(v0.y, 0.f);
            v0.z = fmaxf(v0.z, 0.f); v0.w = fmaxf(v0.w, 0.f);
            v1.x = fmaxf(v1.x, 0.f); v1.y = fmaxf(v1.y, 0.f);
            v1.z = fmaxf(v1.z, 0.f); v1.w = fmaxf(v1.w, 0.f);
        }
        *(float4*)cptr = v0;
        *(float4*)(cptr + 4) = v1;
    }
}

// out[i,0:2] = h[i] @ wl + m2[i] @ wr + b ; one wave per node
__global__ void final_kernel(const float* __restrict__ h, const float* __restrict__ m2,
                             const float* __restrict__ wl, const float* __restrict__ wr,
                             const float* __restrict__ b, float* __restrict__ out, int M) {
    int wave = threadIdx.x >> 6;
    int lane = threadIdx.x & 63;
    int i = blockIdx.x * 4 + wave;
    if (i >= M) return;
    float p0 = 0.f, p1 = 0.f;
    for (int k = lane; k < 256; k += 64) {
        float hv = h[(size_t)i * 256 + k];
        float mv = m2[(size_t)i * 256 + k];
        p0 += hv * wl[2 * k]     + mv * wr[2 * k];
        p1 += hv * wl[2 * k + 1] + mv * wr[2 * k + 1];
    }
#pragma unroll
    for (int off = 32; off > 0; off >>= 1) {
        p0 += __shfl_down(p0, off);
        p1 += __shfl_down(p1, off);
    }
    if (lane == 0) {
        out[(size_t)i * 2 + 0] = p0 + b[0];
        out[(size_t)i * 2 + 1] = p1 + b[1];
    }
}

extern "C" void kernel_launch(void* const* d_in, const int* in_sizes, int n_in,
                              void* d_out, int out_size, void* d_ws, size_t ws_size,
                              hipStream_t stream) {
    const float* x      = (const float*)d_in[0];
    const int*   ei     = (const int*)d_in[1];
    const float* g_w1[3] = {(const float*)d_in[2], (const float*)d_in[6],  (const float*)d_in[10]};
    const float* g_b1[3] = {(const float*)d_in[3], (const float*)d_in[7],  (const float*)d_in[11]};
    const float* g_w2[3] = {(const float*)d_in[4], (const float*)d_in[8],  (const float*)d_in[12]};
    const float* g_b2[3] = {(const float*)d_in[5], (const float*)d_in[9],  (const float*)d_in[13]};
    const float* gout_w = (const float*)d_in[14];
    const float* gout_b = (const float*)d_in[15];
    const float* s0_wl  = (const float*)d_in[16];
    const float* s0_wr  = (const float*)d_in[17];
    const float* s0_b   = (const float*)d_in[18];
    const float* s1_wl  = (const float*)d_in[19];
    const float* s1_wr  = (const float*)d_in[20];
    const float* s1_b   = (const float*)d_in[21];
    float* out = (float*)d_out;

    const int N = in_sizes[0] / 64;
    const int E = in_sizes[1] / 2;

    char* ws = (char*)d_ws;
    size_t o = 0;
    auto take = [&](size_t bytes) -> char* {
        char* p = ws + o;
        o = (o + bytes + 255) & ~(size_t)255;
        return p;
    };
    float* bufA   = (float*)take((size_t)N * 256 * 4);
    float* bufB   = (float*)take((size_t)N * 256 * 4);
    float* bufC   = (float*)take((size_t)N * 256 * 4);
    int*   srcI   = (int*)take((size_t)E * 4);
    int*   dstI   = (int*)take((size_t)E * 4);
    int*   colI   = (int*)take((size_t)E * 4);
    int*   rowptr = (int*)take((size_t)(N + 1) * 4);
    int*   cursor = (int*)take((size_t)N * 4);
    int*   deg    = (int*)take((size_t)N * 4);
    float* invdeg = (float*)take((size_t)N * 4);
    int*   flag   = (int*)take(4);

    hipMemsetAsync(deg, 0, (size_t)N * 4, stream);
    hipMemsetAsync(flag, 1, 4, stream);   // 0x01010101 != 0 -> "assume int64"

    const int TB = 256;
    // --- graph preprocessing: CSR by dst ---
    detect_kernel<<<4, TB, 0, stream>>>(ei, 1024, flag);
    convert_kernel<<<(E + TB - 1) / TB, TB, 0, stream>>>(ei, E, flag, srcI, dstI);
    deg_kernel<<<(E + TB - 1) / TB, TB, 0, stream>>>(dstI, E, deg);
    scan_kernel<<<1, 1024, 0, stream>>>(deg, N, rowptr, cursor);
    invdeg_kernel<<<(N + TB - 1) / TB, TB, 0, stream>>>(deg, N, invdeg);
    scatter_kernel<<<(E + TB - 1) / TB, TB, 0, stream>>>(srcI, dstI, E, cursor, colI);

    auto gemm = [&](const float* A, int lda, const float* W, const float* bias, float* C,
                    int M, int K, int Nc, int flags) {
        dim3 grid((M + GBM - 1) / GBM, Nc / GBN);
        gemm2_kernel<<<grid, 256, 0, stream>>>(A, lda, W, Nc, bias, C, M, K, flags);
    };
    const int AGG_GRID = (N + 3) / 4;

    // h0 = x[:, :32]
    slice_kernel<<<((N * 32) + TB - 1) / TB, TB, 0, stream>>>(x, bufA, N * 32);

    // --- GIN layer 0 (C=32 -> 128) ---
    agg2_kernel<32, 1, 0><<<AGG_GRID, 256, 0, stream>>>(bufA, 32, rowptr, colI, invdeg, bufB, 32, N);
    gemm(bufB, 32, g_w1[0], g_b1[0], bufC, N, 32, 128, FLAG_BIAS | FLAG_RELU);
    gemm(bufC, 128, g_w2[0], g_b2[0], bufA, N, 128, 128, FLAG_BIAS | FLAG_RELU);

    // --- GIN layers 1,2 (C=128) ---
    for (int l = 1; l < 3; ++l) {
        agg2_kernel<128, 2, 0><<<AGG_GRID, 256, 0, stream>>>(bufA, 128, rowptr, colI, invdeg, bufB, 128, N);
        gemm(bufB, 128, g_w1[l], g_b1[l], bufC, N, 128, 128, FLAG_BIAS | FLAG_RELU);
        gemm(bufC, 128, g_w2[l], g_b2[l], bufA, N, 128, 128, FLAG_BIAS | FLAG_RELU);
    }

    // gin_out = h @ gout_w + gout_b    (bufA -> bufB)
    gemm(bufA, 128, gout_w, gout_b, bufB, N, 128, 128, FLAG_BIAS);

    // hcat = [x | gin_out] (192 wide)  -> bufC
    concat_kernel<<<((N * 192) + TB - 1) / TB, TB, 0, stream>>>(x, bufB, bufC, N * 192);

    // mean1 = [agg(x) | agg(gin_out)] * inv_deg  -> bufA (192-wide, strided)
    agg2_kernel<64, 1, 1><<<AGG_GRID, 256, 0, stream>>>(x, 64, rowptr, colI, invdeg, bufA, 192, N);
    agg2_kernel<128, 2, 1><<<AGG_GRID, 256, 0, stream>>>(bufB, 128, rowptr, colI, invdeg, bufA + 64, 192, N);

    // s0: relu(hcat @ wl + mean1 @ wr + b) -> bufB (256 wide)
    gemm(bufC, 192, s0_wl, s0_b, bufB, N, 192, 256, FLAG_BIAS);
    gemm(bufA, 192, s0_wr, nullptr, bufB, N, 192, 256, FLAG_ADD | FLAG_RELU);

    // mean2 = agg(h) * inv_deg (256 wide)  bufB -> bufC
    agg2_kernel<256, 4, 1><<<AGG_GRID, 256, 0, stream>>>(bufB, 256, rowptr, colI, invdeg, bufC, 256, N);

    // out = h @ s1_wl + mean2 @ s1_wr + b
    final_kernel<<<(N + 3) / 4, 256, 0, stream>>>(bufB, bufC, s1_wl, s1_wr, s1_b, out, N);
}

// Round 3
// 626.761 us; speedup vs baseline: 1.7655x; 1.5114x over previous
//
#include <hip/hip_runtime.h>

// ---------------------------------------------------------------------------
// GAMLNET GNN forward, bf16 edition.
// N=50000, E=800000, F=64, GIN_F=32, H1=128, H2=256, OUT=2
// R2: all intermediate node features stored bf16 (fp32 accumulate),
// MFMA 16x16x32 bf16 GEMM (128x128 tile), dual-A fused SAGE GEMM,
// bf16 vectorized gather aggregation.
// ---------------------------------------------------------------------------

typedef unsigned short ushort_t;
typedef __bf16 bf16x8 __attribute__((ext_vector_type(8)));
typedef float f32x4 __attribute__((ext_vector_type(4)));

#define FLAG_BIAS 1
#define FLAG_RELU 4

__device__ __forceinline__ float b2f(unsigned int u16) {
    union { unsigned int i; float f; } v;
    v.i = u16 << 16;
    return v.f;
}
__device__ __forceinline__ unsigned short f2b(float f) {
    union { float f; unsigned int i; } v;
    v.f = f;
    unsigned int x = v.i;
    unsigned int r = (x + 0x7fffu + ((x >> 16) & 1u)) >> 16;  // RNE
    return (unsigned short)r;
}

// --- edge dtype detection: if input is int64, odd int32 words are all zero ---
__global__ void detect_kernel(const int* __restrict__ ei, int ncheck, int* flag) {
    int t = blockIdx.x * blockDim.x + threadIdx.x;
    if (t < ncheck) {
        if (ei[2 * t + 1] != 0) atomicAnd(flag, 0);
    }
}

__global__ void convert_kernel(const int* __restrict__ ei, int E, const int* __restrict__ flag,
                               int* __restrict__ src, int* __restrict__ dst) {
    int e = blockIdx.x * blockDim.x + threadIdx.x;
    if (e >= E) return;
    if (*flag) {
        src[e] = ei[2 * (size_t)e];
        dst[e] = ei[2 * ((size_t)E + e)];
    } else {
        src[e] = ei[e];
        dst[e] = ei[(size_t)E + e];
    }
}

__global__ void deg_kernel(const int* __restrict__ dst, int E, int* __restrict__ deg) {
    int e = blockIdx.x * blockDim.x + threadIdx.x;
    if (e < E) atomicAdd(&deg[dst[e]], 1);
}

__global__ void scan_kernel(const int* __restrict__ deg, int n,
                            int* __restrict__ rowptr, int* __restrict__ cursor) {
    __shared__ int sh[1024];
    __shared__ int carry;
    if (threadIdx.x == 0) carry = 0;
    __syncthreads();
    for (int base = 0; base < n; base += 1024) {
        int i = base + (int)threadIdx.x;
        int v = (i < n) ? deg[i] : 0;
        sh[threadIdx.x] = v;
        __syncthreads();
        for (int off = 1; off < 1024; off <<= 1) {
            int t = 0;
            if ((int)threadIdx.x >= off) t = sh[threadIdx.x - off];
            __syncthreads();
            sh[threadIdx.x] += t;
            __syncthreads();
        }
        int incl = sh[threadIdx.x];
        int c0 = carry;
        int excl = c0 + incl - v;
        if (i < n) { rowptr[i] = excl; cursor[i] = excl; }
        __syncthreads();
        if (threadIdx.x == 1023) carry = c0 + sh[1023];
        __syncthreads();
    }
    if (threadIdx.x == 0) rowptr[n] = carry;
}

__global__ void invdeg_kernel(const int* __restrict__ deg, int n, float* __restrict__ invdeg) {
    int i = blockIdx.x * blockDim.x + threadIdx.x;
    if (i < n) invdeg[i] = 1.0f / fmaxf((float)deg[i], 1.0f);
}

__global__ void scatter_kernel(const int* __restrict__ src, const int* __restrict__ dst, int E,
                               int* __restrict__ cursor, int* __restrict__ col) {
    int e = blockIdx.x * blockDim.x + threadIdx.x;
    if (e < E) {
        int p = atomicAdd(&cursor[dst[e]], 1);
        col[p] = src[e];
    }
}

// x (fp32, N x 64) -> xb (bf16, N x 64) and h0b (bf16, N x 32 slice)
__global__ void xconv_kernel(const float* __restrict__ x, ushort_t* __restrict__ xb,
                             ushort_t* __restrict__ h0b, int total16) {
    int idx = blockIdx.x * blockDim.x + threadIdx.x;
    if (idx >= total16) return;
    int node = idx >> 4, seg = idx & 15;
    float4 v = *(const float4*)&x[(size_t)node * 64 + seg * 4];
    ushort4 u;
    u.x = f2b(v.x); u.y = f2b(v.y); u.z = f2b(v.z); u.w = f2b(v.w);
    *(ushort4*)&xb[(size_t)node * 64 + seg * 4] = u;
    if (seg < 8) *(ushort4*)&h0b[(size_t)node * 32 + seg * 4] = u;
}

// fused weight convert+transpose: dst[n*K+k] = bf16(src[k*N+n])
struct WtDesc { const float* src; ushort_t* dst; int K; int N; int base; };
struct WtArgs { WtDesc d[9]; int total; };
__global__ void wtconv_kernel(WtArgs a) {
    int idx = blockIdx.x * blockDim.x + threadIdx.x;
    if (idx >= a.total) return;
    int s = 0;
#pragma unroll
    for (int i = 1; i < 9; ++i) if (idx >= a.d[i].base) s = i;
    int local = idx - a.d[s].base;
    int K = a.d[s].K, Nn = a.d[s].N;
    int n = local / K, k = local - n * K;
    a.d[s].dst[(size_t)n * K + k] = f2b(a.d[s].src[(size_t)k * Nn + n]);
}

// hcat = [xb (64) | ginb (128)] -> 192-wide bf16, via uint4 (8 bf16) groups
__global__ void concatb_kernel(const ushort_t* __restrict__ xb, const ushort_t* __restrict__ ginb,
                               ushort_t* __restrict__ hcat, int totalg) {
    int idx = blockIdx.x * blockDim.x + threadIdx.x;
    if (idx >= totalg) return;
    int node = idx / 24, g = idx % 24;
    uint4 v;
    if (g < 8) v = ((const uint4*)xb)[(size_t)node * 8 + g];
    else       v = ((const uint4*)ginb)[(size_t)node * 16 + (g - 8)];
    ((uint4*)hcat)[idx] = v;
}

// ---------------------------------------------------------------------------
// bf16 gather aggregation: one wave per node, lane handles VEC bf16.
// MODE 0: out[i] = h[i] + sum_nbr h[j]   MODE 1: out[i] = invdeg[i]*sum h[j]
// ---------------------------------------------------------------------------
template <int VEC>
__device__ __forceinline__ void ldrow(const ushort_t* p, float* t) {
    if constexpr (VEC == 1) {
        t[0] = b2f(p[0]);
    } else if constexpr (VEC == 2) {
        unsigned int v = *(const unsigned int*)p;
        t[0] = b2f(v & 0xffffu); t[1] = b2f(v >> 16);
    } else {
        uint2 v = *(const uint2*)p;
        t[0] = b2f(v.x & 0xffffu); t[1] = b2f(v.x >> 16);
        t[2] = b2f(v.y & 0xffffu); t[3] = b2f(v.y >> 16);
    }
}

template <int VEC, int MODE>
__global__ __launch_bounds__(256) void aggb_kernel(
    const ushort_t* __restrict__ h, int ldh,
    const int* __restrict__ rowptr, const int* __restrict__ col,
    const float* __restrict__ invdeg,
    ushort_t* __restrict__ out, int ldo, int Nn, int lanes) {
    int wid = blockIdx.x * 4 + ((int)threadIdx.x >> 6);
    int lane = (int)threadIdx.x & 63;
    if (wid >= Nn || lane >= lanes) return;

    const ushort_t* hb = h + (size_t)lane * VEC;
    float a[VEC];
#pragma unroll
    for (int v = 0; v < VEC; ++v) a[v] = 0.f;

    int p0 = rowptr[wid], p1 = rowptr[wid + 1];
    int p = p0;
    for (; p + 4 <= p1; p += 4) {
        int j0 = col[p], j1 = col[p + 1], j2 = col[p + 2], j3 = col[p + 3];
        float t0[VEC], t1[VEC], t2[VEC], t3[VEC];
        ldrow<VEC>(hb + (size_t)j0 * ldh, t0);
        ldrow<VEC>(hb + (size_t)j1 * ldh, t1);
        ldrow<VEC>(hb + (size_t)j2 * ldh, t2);
        ldrow<VEC>(hb + (size_t)j3 * ldh, t3);
#pragma unroll
        for (int v = 0; v < VEC; ++v) a[v] += (t0[v] + t1[v]) + (t2[v] + t3[v]);
    }
    for (; p < p1; ++p) {
        float t[VEC];
        ldrow<VEC>(hb + (size_t)col[p] * ldh, t);
#pragma unroll
        for (int v = 0; v < VEC; ++v) a[v] += t[v];
    }

    if constexpr (MODE == 0) {
        float t[VEC];
        ldrow<VEC>(hb + (size_t)wid * ldh, t);
#pragma unroll
        for (int v = 0; v < VEC; ++v) a[v] += t[v];
    } else {
        float s = invdeg[wid];
#pragma unroll
        for (int v = 0; v < VEC; ++v) a[v] *= s;
    }

    ushort_t* op = out + (size_t)wid * ldo + (size_t)lane * VEC;
    if constexpr (VEC == 1) {
        op[0] = f2b(a[0]);
    } else if constexpr (VEC == 2) {
        unsigned int v = (unsigned int)f2b(a[0]) | ((unsigned int)f2b(a[1]) << 16);
        *(unsigned int*)op = v;
    } else {
        uint2 v;
        v.x = (unsigned int)f2b(a[0]) | ((unsigned int)f2b(a[1]) << 16);
        v.y = (unsigned int)f2b(a[2]) | ((unsigned int)f2b(a[3]) << 16);
        *(uint2*)op = v;
    }
}

// ---------------------------------------------------------------------------
// bf16 MFMA GEMM: C = act(A1@W1 [+ A2@W2] + bias), Wt pre-transposed [Nc][K].
// 128x128 tile, 4 waves (each 64x64 = 4x4 MFMA tiles), K-step 32.
// LDS rows padded to 40 ushorts (80 B) -> 16B-aligned ds_read_b128, ~2-way banks.
// ---------------------------------------------------------------------------
__global__ __launch_bounds__(256) void mgemm_kernel(
    const ushort_t* __restrict__ A1, int lda1, const ushort_t* __restrict__ W1,
    const ushort_t* __restrict__ A2, int lda2, const ushort_t* __restrict__ W2,
    int K, int M, int Nc, const float* __restrict__ bias,
    ushort_t* __restrict__ Cb, int ldc, int flags) {
    __shared__ __align__(16) ushort_t Ash[128 * 40];
    __shared__ __align__(16) ushort_t Wsh[128 * 40];

    int rowbase = blockIdx.x * 128, colbase = blockIdx.y * 128;
    int tid = threadIdx.x;
    int lane = tid & 63, wid = tid >> 6;
    int wr = wid >> 1, wc = wid & 1;
    int lr = lane & 15, lk = (lane >> 4) * 8;

    f32x4 acc[4][4];
#pragma unroll
    for (int i = 0; i < 4; ++i)
#pragma unroll
        for (int j = 0; j < 4; ++j) acc[i][j] = (f32x4){0.f, 0.f, 0.f, 0.f};

    for (int pass = 0; pass < 2; ++pass) {
        const ushort_t* A = pass ? A2 : A1;
        const ushort_t* W = pass ? W2 : W1;
        int lda = pass ? lda2 : lda1;
        if (!A) break;
        for (int ko = 0; ko < K; ko += 32) {
#pragma unroll
            for (int s = 0; s < 2; ++s) {
                int idx = tid + 256 * s;     // 0..511
                int row = idx >> 2;          // 0..127
                int seg = idx & 3;           // 16B segment along k
                uint4 va = make_uint4(0u, 0u, 0u, 0u);
                int gr = rowbase + row;
                if (gr < M) va = *(const uint4*)&A[(size_t)gr * lda + ko + seg * 8];
                *(uint4*)&Ash[row * 40 + seg * 8] = va;
                *(uint4*)&Wsh[row * 40 + seg * 8] =
                    *(const uint4*)&W[(size_t)(colbase + row) * K + ko + seg * 8];
            }
            __syncthreads();
            bf16x8 af[4], bfr[4];
#pragma unroll
            for (int i = 0; i < 4; ++i)
                af[i] = *(const bf16x8*)&Ash[(wr * 64 + i * 16 + lr) * 40 + lk];
#pragma unroll
            for (int j = 0; j < 4; ++j)
                bfr[j] = *(const bf16x8*)&Wsh[(wc * 64 + j * 16 + lr) * 40 + lk];
#pragma unroll
            for (int i = 0; i < 4; ++i)
#pragma unroll
                for (int j = 0; j < 4; ++j)
                    acc[i][j] = __builtin_amdgcn_mfma_f32_16x16x32_bf16(af[i], bfr[j], acc[i][j], 0, 0, 0);
            __syncthreads();
        }
        if (pass == 1) break;
    }

    int rq = (lane >> 4) * 4;
#pragma unroll
    for (int j = 0; j < 4; ++j) {
        int c = colbase + wc * 64 + j * 16 + lr;
        float bv = (flags & FLAG_BIAS) ? bias[c] : 0.f;
#pragma unroll
        for (int i = 0; i < 4; ++i) {
            int r0 = rowbase + wr * 64 + i * 16 + rq;
#pragma unroll
            for (int t = 0; t < 4; ++t) {
                int r = r0 + t;
                if (r >= M) continue;
                float v = acc[i][j][t] + bv;
                if (flags & FLAG_RELU) v = fmaxf(v, 0.f);
                Cb[(size_t)r * ldc + c] = f2b(v);
            }
        }
    }
}

// out[i,0:2] = h[i] @ wl + m2[i] @ wr + b ; one wave per node (bf16 inputs)
__global__ void finalb_kernel(const ushort_t* __restrict__ h, const ushort_t* __restrict__ m2,
                              const float* __restrict__ wl, const float* __restrict__ wr,
                              const float* __restrict__ b, float* __restrict__ out, int M) {
    int wave = threadIdx.x >> 6;
    int lane = threadIdx.x & 63;
    int i = blockIdx.x * 4 + wave;
    if (i >= M) return;
    float p0 = 0.f, p1 = 0.f;
    for (int k = lane; k < 256; k += 64) {
        float hv = b2f(h[(size_t)i * 256 + k]);
        float mv = b2f(m2[(size_t)i * 256 + k]);
        float2 wlv = *(const float2*)&wl[2 * k];
        float2 wrv = *(const float2*)&wr[2 * k];
        p0 += hv * wlv.x + mv * wrv.x;
        p1 += hv * wlv.y + mv * wrv.y;
    }
#pragma unroll
    for (int off = 32; off > 0; off >>= 1) {
        p0 += __shfl_down(p0, off);
        p1 += __shfl_down(p1, off);
    }
    if (lane == 0) {
        out[(size_t)i * 2 + 0] = p0 + b[0];
        out[(size_t)i * 2 + 1] = p1 + b[1];
    }
}

extern "C" void kernel_launch(void* const* d_in, const int* in_sizes, int n_in,
                              void* d_out, int out_size, void* d_ws, size_t ws_size,
                              hipStream_t stream) {
    const float* x      = (const float*)d_in[0];
    const int*   ei     = (const int*)d_in[1];
    const float* g_w1[3] = {(const float*)d_in[2], (const float*)d_in[6],  (const float*)d_in[10]};
    const float* g_b1[3] = {(const float*)d_in[3], (const float*)d_in[7],  (const float*)d_in[11]};
    const float* g_w2[3] = {(const float*)d_in[4], (const float*)d_in[8],  (const float*)d_in[12]};
    const float* g_b2[3] = {(const float*)d_in[5], (const float*)d_in[9],  (const float*)d_in[13]};
    const float* gout_w = (const float*)d_in[14];
    const float* gout_b = (const float*)d_in[15];
    const float* s0_wl  = (const float*)d_in[16];
    const float* s0_wr  = (const float*)d_in[17];
    const float* s0_b   = (const float*)d_in[18];
    const float* s1_wl  = (const float*)d_in[19];
    const float* s1_wr  = (const float*)d_in[20];
    const float* s1_b   = (const float*)d_in[21];
    float* out = (float*)d_out;

    const int N = in_sizes[0] / 64;
    const int E = in_sizes[1] / 2;

    char* ws = (char*)d_ws;
    size_t o = 0;
    auto take = [&](size_t bytes) -> char* {
        char* p = ws + o;
        o = (o + bytes + 255) & ~(size_t)255;
        return p;
    };
    ushort_t* h0b    = (ushort_t*)take((size_t)N * 32 * 2);
    ushort_t* xb     = (ushort_t*)take((size_t)N * 64 * 2);
    ushort_t* bA     = (ushort_t*)take((size_t)N * 128 * 2);
    ushort_t* bB     = (ushort_t*)take((size_t)N * 128 * 2);
    ushort_t* bC     = (ushort_t*)take((size_t)N * 128 * 2);
    ushort_t* ginb   = (ushort_t*)take((size_t)N * 128 * 2);
    ushort_t* hcatb  = (ushort_t*)take((size_t)N * 192 * 2);
    ushort_t* mean1b = (ushort_t*)take((size_t)N * 192 * 2);
    ushort_t* s0b    = (ushort_t*)take((size_t)N * 256 * 2);
    ushort_t* mean2b = (ushort_t*)take((size_t)N * 256 * 2);
    // transposed bf16 weights
    ushort_t* w1t0 = (ushort_t*)take(128 * 32 * 2);
    ushort_t* w2t0 = (ushort_t*)take(128 * 128 * 2);
    ushort_t* w1t1 = (ushort_t*)take(128 * 128 * 2);
    ushort_t* w2t1 = (ushort_t*)take(128 * 128 * 2);
    ushort_t* w1t2 = (ushort_t*)take(128 * 128 * 2);
    ushort_t* w2t2 = (ushort_t*)take(128 * 128 * 2);
    ushort_t* goutt = (ushort_t*)take(128 * 128 * 2);
    ushort_t* s0wlt = (ushort_t*)take(256 * 192 * 2);
    ushort_t* s0wrt = (ushort_t*)take(256 * 192 * 2);
    int*   srcI   = (int*)take((size_t)E * 4);
    int*   dstI   = (int*)take((size_t)E * 4);
    int*   colI   = (int*)take((size_t)E * 4);
    int*   rowptr = (int*)take((size_t)(N + 1) * 4);
    int*   cursor = (int*)take((size_t)N * 4);
    int*   deg    = (int*)take((size_t)N * 4);
    float* invdeg = (float*)take((size_t)N * 4);
    int*   flag   = (int*)take(4);

    hipMemsetAsync(deg, 0, (size_t)N * 4, stream);
    hipMemsetAsync(flag, 1, 4, stream);

    const int TB = 256;
    // --- CSR by dst ---
    detect_kernel<<<4, TB, 0, stream>>>(ei, 1024, flag);
    convert_kernel<<<(E + TB - 1) / TB, TB, 0, stream>>>(ei, E, flag, srcI, dstI);
    deg_kernel<<<(E + TB - 1) / TB, TB, 0, stream>>>(dstI, E, deg);
    scan_kernel<<<1, 1024, 0, stream>>>(deg, N, rowptr, cursor);
    invdeg_kernel<<<(N + TB - 1) / TB, TB, 0, stream>>>(deg, N, invdeg);
    scatter_kernel<<<(E + TB - 1) / TB, TB, 0, stream>>>(srcI, dstI, E, cursor, colI);

    // --- weight convert+transpose (one fused kernel) ---
    WtArgs wa;
    const float* wsrc[9] = {g_w1[0], g_w2[0], g_w1[1], g_w2[1], g_w1[2], g_w2[2], gout_w, s0_wl, s0_wr};
    ushort_t* wdst[9]    = {w1t0,    w2t0,    w1t1,    w2t1,    w1t2,    w2t2,    goutt,  s0wlt, s0wrt};
    int wk[9] = {32, 128, 128, 128, 128, 128, 128, 192, 192};
    int wn[9] = {128, 128, 128, 128, 128, 128, 128, 256, 256};
    int base = 0;
    for (int i = 0; i < 9; ++i) {
        wa.d[i].src = wsrc[i]; wa.d[i].dst = wdst[i];
        wa.d[i].K = wk[i]; wa.d[i].N = wn[i]; wa.d[i].base = base;
        base += wk[i] * wn[i];
    }
    wa.total = base;
    wtconv_kernel<<<(base + TB - 1) / TB, TB, 0, stream>>>(wa);

    // --- x -> bf16 (xb) + slice (h0b) ---
    xconv_kernel<<<((N * 16) + TB - 1) / TB, TB, 0, stream>>>(x, xb, h0b, N * 16);

    auto gemm = [&](const ushort_t* A1, int lda1, const ushort_t* W1,
                    const ushort_t* A2, int lda2, const ushort_t* W2,
                    int K, int Nc, const float* bias, ushort_t* C, int ldc, int flags) {
        dim3 grid((N + 127) / 128, Nc / 128);
        mgemm_kernel<<<grid, 256, 0, stream>>>(A1, lda1, W1, A2, lda2, W2, K, N, Nc, bias, C, ldc, flags);
    };
    const int AGG_GRID = (N + 3) / 4;

    // --- GIN layer 0 (C=32 -> 128) ---
    aggb_kernel<1, 0><<<AGG_GRID, 256, 0, stream>>>(h0b, 32, rowptr, colI, invdeg, bB, 32, N, 32);
    gemm(bB, 32, w1t0, nullptr, 0, nullptr, 32, 128, g_b1[0], bC, 128, FLAG_BIAS | FLAG_RELU);
    gemm(bC, 128, w2t0, nullptr, 0, nullptr, 128, 128, g_b2[0], bA, 128, FLAG_BIAS | FLAG_RELU);

    // --- GIN layers 1,2 (C=128) ---
    ushort_t* w1s[3] = {w1t0, w1t1, w1t2};
    ushort_t* w2s[3] = {w2t0, w2t1, w2t2};
    for (int l = 1; l < 3; ++l) {
        aggb_kernel<2, 0><<<AGG_GRID, 256, 0, stream>>>(bA, 128, rowptr, colI, invdeg, bB, 128, N, 64);
        gemm(bB, 128, w1s[l], nullptr, 0, nullptr, 128, 128, g_b1[l], bC, 128, FLAG_BIAS | FLAG_RELU);
        gemm(bC, 128, w2s[l], nullptr, 0, nullptr, 128, 128, g_b2[l], bA, 128, FLAG_BIAS | FLAG_RELU);
    }

    // gin_out = h @ gout_w + gout_b   (bA -> ginb)
    gemm(bA, 128, goutt, nullptr, 0, nullptr, 128, 128, gout_b, ginb, 128, FLAG_BIAS);

    // hcat = [xb | ginb] (192 wide)
    concatb_kernel<<<((N * 24) + TB - 1) / TB, TB, 0, stream>>>(xb, ginb, hcatb, N * 24);

    // mean1 = [agg(xb) | agg(ginb)] * inv_deg -> mean1b (192-wide, strided)
    aggb_kernel<1, 1><<<AGG_GRID, 256, 0, stream>>>(xb, 64, rowptr, colI, invdeg, mean1b, 192, N, 64);
    aggb_kernel<2, 1><<<AGG_GRID, 256, 0, stream>>>(ginb, 128, rowptr, colI, invdeg, mean1b + 64, 192, N, 64);

    // s0 = relu(hcat @ wl + mean1 @ wr + b)  (fused dual-A GEMM, Nc=256)
    gemm(hcatb, 192, s0wlt, mean1b, 192, s0wrt, 192, 256, s0_b, s0b, 256, FLAG_BIAS | FLAG_RELU);

    // mean2 = agg(s0) * inv_deg (256 wide)
    aggb_kernel<4, 1><<<AGG_GRID, 256, 0, stream>>>(s0b, 256, rowptr, colI, invdeg, mean2b, 256, N, 64);

    // out = s0 @ s1_wl + mean2 @ s1_wr + b
    finalb_kernel<<<(N + 3) / 4, 256, 0, stream>>>(s0b, mean2b, s1_wl, s1_wr, s1_b, out, N);
}

// Round 4
// 488.593 us; speedup vs baseline: 2.2648x; 1.2828x over previous
//
#include <hip/hip_runtime.h>

// ---------------------------------------------------------------------------
// GAMLNET GNN forward, bf16 edition, R3.
// R3: multi-block scan (was 94us single-block), project-before-agg for mean2
// (C=256 gather -> C=2 fp32 gather), 4-pass MFMA GEMM kills concat kernel.
// ---------------------------------------------------------------------------

typedef unsigned short ushort_t;
typedef __bf16 bf16x8 __attribute__((ext_vector_type(8)));
typedef float f32x4 __attribute__((ext_vector_type(4)));

#define FLAG_BIAS 1
#define FLAG_RELU 4

__device__ __forceinline__ float b2f(unsigned int u16) {
    union { unsigned int i; float f; } v;
    v.i = u16 << 16;
    return v.f;
}
__device__ __forceinline__ unsigned short f2b(float f) {
    union { float f; unsigned int i; } v;
    v.f = f;
    unsigned int x = v.i;
    unsigned int r = (x + 0x7fffu + ((x >> 16) & 1u)) >> 16;  // RNE
    return (unsigned short)r;
}

// --- edge dtype detection: if input is int64, odd int32 words are all zero ---
__global__ void detect_kernel(const int* __restrict__ ei, int ncheck, int* flag) {
    int t = blockIdx.x * blockDim.x + threadIdx.x;
    if (t < ncheck) {
        if (ei[2 * t + 1] != 0) atomicAnd(flag, 0);
    }
}

__global__ void convert_kernel(const int* __restrict__ ei, int E, const int* __restrict__ flag,
                               int* __restrict__ src, int* __restrict__ dst) {
    int e = blockIdx.x * blockDim.x + threadIdx.x;
    if (e >= E) return;
    if (*flag) {
        src[e] = ei[2 * (size_t)e];
        dst[e] = ei[2 * ((size_t)E + e)];
    } else {
        src[e] = ei[e];
        dst[e] = ei[(size_t)E + e];
    }
}

__global__ void deg_kernel(const int* __restrict__ dst, int E, int* __restrict__ deg) {
    int e = blockIdx.x * blockDim.x + threadIdx.x;
    if (e < E) atomicAdd(&deg[dst[e]], 1);
}

// --- 3-phase multi-block exclusive scan (2048 elements per block) ---
__global__ __launch_bounds__(256) void scanA_kernel(const int* __restrict__ deg, int n,
                                                    int* __restrict__ rowptr,
                                                    int* __restrict__ blocksum) {
    __shared__ int sh[256];
    int b = blockIdx.x, tid = threadIdx.x;
    int base = b * 2048 + tid * 8;
    int v[8];
#pragma unroll
    for (int e = 0; e < 8; ++e) {
        int i = base + e;
        v[e] = (i < n) ? deg[i] : 0;
    }
    int t = 0;
#pragma unroll
    for (int e = 0; e < 8; ++e) { int x = v[e]; v[e] = t; t += x; }
    sh[tid] = t;
    __syncthreads();
    for (int off = 1; off < 256; off <<= 1) {
        int val = (tid >= off) ? sh[tid - off] : 0;
        __syncthreads();
        sh[tid] += val;
        __syncthreads();
    }
    int excl = sh[tid] - t;
#pragma unroll
    for (int e = 0; e < 8; ++e) {
        int i = base + e;
        if (i < n) rowptr[i] = excl + v[e];
    }
    if (tid == 255) blocksum[b] = sh[255];
}

__global__ __launch_bounds__(256) void scanB_kernel(const int* __restrict__ blocksum, int nb,
                                                    int* __restrict__ blockoff,
                                                    int* __restrict__ rowptr, int n) {
    __shared__ int sh[256];
    int tid = threadIdx.x;
    int v = (tid < nb) ? blocksum[tid] : 0;
    sh[tid] = v;
    __syncthreads();
    for (int off = 1; off < 256; off <<= 1) {
        int t = (tid >= off) ? sh[tid - off] : 0;
        __syncthreads();
        sh[tid] += t;
        __syncthreads();
    }
    if (tid < nb) blockoff[tid] = sh[tid] - v;
    if (tid == 255) rowptr[n] = sh[255];
}

__global__ void scanC_kernel(const int* __restrict__ deg, int n, const int* __restrict__ blockoff,
                             int* __restrict__ rowptr, int* __restrict__ cursor,
                             float* __restrict__ invdeg) {
    int i = blockIdx.x * blockDim.x + threadIdx.x;
    if (i >= n) return;
    int r = rowptr[i] + blockoff[i >> 11];
    rowptr[i] = r;
    cursor[i] = r;
    invdeg[i] = 1.0f / fmaxf((float)deg[i], 1.0f);
}

__global__ void scatter_kernel(const int* __restrict__ src, const int* __restrict__ dst, int E,
                               int* __restrict__ cursor, int* __restrict__ col) {
    int e = blockIdx.x * blockDim.x + threadIdx.x;
    if (e < E) {
        int p = atomicAdd(&cursor[dst[e]], 1);
        col[p] = src[e];
    }
}

// x (fp32, N x 64) -> xb (bf16, N x 64)
__global__ void xconv_kernel(const float* __restrict__ x, ushort_t* __restrict__ xb, int total16) {
    int idx = blockIdx.x * blockDim.x + threadIdx.x;
    if (idx >= total16) return;
    float4 v = *(const float4*)&x[(size_t)idx * 4];
    ushort4 u;
    u.x = f2b(v.x); u.y = f2b(v.y); u.z = f2b(v.z); u.w = f2b(v.w);
    *(ushort4*)&xb[(size_t)idx * 4] = u;
}

// fused weight convert+transpose: dst[n*K+k] = bf16(src[k*N+n])
struct WtDesc { const float* src; ushort_t* dst; int K; int N; int base; };
struct WtArgs { WtDesc d[11]; int total; };
__global__ void wtconv_kernel(WtArgs a) {
    int idx = blockIdx.x * blockDim.x + threadIdx.x;
    if (idx >= a.total) return;
    int s = 0;
#pragma unroll
    for (int i = 1; i < 11; ++i) if (idx >= a.d[i].base) s = i;
    int local = idx - a.d[s].base;
    int K = a.d[s].K, Nn = a.d[s].N;
    int n = local / K, k = local - n * K;
    a.d[s].dst[(size_t)n * K + k] = f2b(a.d[s].src[(size_t)k * Nn + n]);
}

// ---------------------------------------------------------------------------
// bf16 gather aggregation: one wave per node, lane handles VEC bf16.
// MODE 0: out[i] = h[i] + sum_nbr h[j]   MODE 1: out[i] = invdeg[i]*sum h[j]
// ---------------------------------------------------------------------------
template <int VEC>
__device__ __forceinline__ void ldrow(const ushort_t* p, float* t) {
    if constexpr (VEC == 1) {
        t[0] = b2f(p[0]);
    } else if constexpr (VEC == 2) {
        unsigned int v = *(const unsigned int*)p;
        t[0] = b2f(v & 0xffffu); t[1] = b2f(v >> 16);
    } else {
        uint2 v = *(const uint2*)p;
        t[0] = b2f(v.x & 0xffffu); t[1] = b2f(v.x >> 16);
        t[2] = b2f(v.y & 0xffffu); t[3] = b2f(v.y >> 16);
    }
}

template <int VEC, int MODE>
__global__ __launch_bounds__(256) void aggb_kernel(
    const ushort_t* __restrict__ h, int ldh,
    const int* __restrict__ rowptr, const int* __restrict__ col,
    const float* __restrict__ invdeg,
    ushort_t* __restrict__ out, int ldo, int Nn, int lanes) {
    int wid = blockIdx.x * 4 + ((int)threadIdx.x >> 6);
    int lane = (int)threadIdx.x & 63;
    if (wid >= Nn || lane >= lanes) return;

    const ushort_t* hb = h + (size_t)lane * VEC;
    float a[VEC];
#pragma unroll
    for (int v = 0; v < VEC; ++v) a[v] = 0.f;

    int p0 = rowptr[wid], p1 = rowptr[wid + 1];
    int p = p0;
    for (; p + 4 <= p1; p += 4) {
        int j0 = col[p], j1 = col[p + 1], j2 = col[p + 2], j3 = col[p + 3];
        float t0[VEC], t1[VEC], t2[VEC], t3[VEC];
        ldrow<VEC>(hb + (size_t)j0 * ldh, t0);
        ldrow<VEC>(hb + (size_t)j1 * ldh, t1);
        ldrow<VEC>(hb + (size_t)j2 * ldh, t2);
        ldrow<VEC>(hb + (size_t)j3 * ldh, t3);
#pragma unroll
        for (int v = 0; v < VEC; ++v) a[v] += (t0[v] + t1[v]) + (t2[v] + t3[v]);
    }
    for (; p < p1; ++p) {
        float t[VEC];
        ldrow<VEC>(hb + (size_t)col[p] * ldh, t);
#pragma unroll
        for (int v = 0; v < VEC; ++v) a[v] += t[v];
    }

    if constexpr (MODE == 0) {
        float t[VEC];
        ldrow<VEC>(hb + (size_t)wid * ldh, t);
#pragma unroll
        for (int v = 0; v < VEC; ++v) a[v] += t[v];
    } else {
        float s = invdeg[wid];
#pragma unroll
        for (int v = 0; v < VEC; ++v) a[v] *= s;
    }

    ushort_t* op = out + (size_t)wid * ldo + (size_t)lane * VEC;
    if constexpr (VEC == 1) {
        op[0] = f2b(a[0]);
    } else if constexpr (VEC == 2) {
        unsigned int v = (unsigned int)f2b(a[0]) | ((unsigned int)f2b(a[1]) << 16);
        *(unsigned int*)op = v;
    } else {
        uint2 v;
        v.x = (unsigned int)f2b(a[0]) | ((unsigned int)f2b(a[1]) << 16);
        v.y = (unsigned int)f2b(a[2]) | ((unsigned int)f2b(a[3]) << 16);
        *(uint2*)op = v;
    }
}

// ---------------------------------------------------------------------------
// bf16 MFMA GEMM, up to 4 (A,W) passes summed: C = act(sum_q Aq@Wq + bias)
// Wt pre-transposed [Nc][K]. 128x128 tile, 4 waves, K-step 32.
// ---------------------------------------------------------------------------
struct GPass { const ushort_t* A; const ushort_t* W; int lda; int K; };
struct GArgs { GPass p[4]; int np; };

__global__ __launch_bounds__(256) void mgemm_kernel(
    GArgs ga, int M, int Nc, const float* __restrict__ bias,
    ushort_t* __restrict__ Cb, int ldc, int flags) {
    __shared__ __align__(16) ushort_t Ash[128 * 40];
    __shared__ __align__(16) ushort_t Wsh[128 * 40];

    int rowbase = blockIdx.x * 128, colbase = blockIdx.y * 128;
    int tid = threadIdx.x;
    int lane = tid & 63, wid = tid >> 6;
    int wr = wid >> 1, wc = wid & 1;
    int lr = lane & 15, lk = (lane >> 4) * 8;

    f32x4 acc[4][4];
#pragma unroll
    for (int i = 0; i < 4; ++i)
#pragma unroll
        for (int j = 0; j < 4; ++j) acc[i][j] = (f32x4){0.f, 0.f, 0.f, 0.f};

    for (int q = 0; q < ga.np; ++q) {
        const ushort_t* A = ga.p[q].A;
        const ushort_t* W = ga.p[q].W;
        int lda = ga.p[q].lda, K = ga.p[q].K;
        for (int ko = 0; ko < K; ko += 32) {
#pragma unroll
            for (int s = 0; s < 2; ++s) {
                int idx = tid + 256 * s;     // 0..511
                int row = idx >> 2;          // 0..127
                int seg = idx & 3;           // 16B segment along k
                uint4 va = make_uint4(0u, 0u, 0u, 0u);
                int gr = rowbase + row;
                if (gr < M) va = *(const uint4*)&A[(size_t)gr * lda + ko + seg * 8];
                *(uint4*)&Ash[row * 40 + seg * 8] = va;
                *(uint4*)&Wsh[row * 40 + seg * 8] =
                    *(const uint4*)&W[(size_t)(colbase + row) * K + ko + seg * 8];
            }
            __syncthreads();
            bf16x8 af[4], bfr[4];
#pragma unroll
            for (int i = 0; i < 4; ++i)
                af[i] = *(const bf16x8*)&Ash[(wr * 64 + i * 16 + lr) * 40 + lk];
#pragma unroll
            for (int j = 0; j < 4; ++j)
                bfr[j] = *(const bf16x8*)&Wsh[(wc * 64 + j * 16 + lr) * 40 + lk];
#pragma unroll
            for (int i = 0; i < 4; ++i)
#pragma unroll
                for (int j = 0; j < 4; ++j)
                    acc[i][j] = __builtin_amdgcn_mfma_f32_16x16x32_bf16(af[i], bfr[j], acc[i][j], 0, 0, 0);
            __syncthreads();
        }
    }

    int rq = (lane >> 4) * 4;
#pragma unroll
    for (int j = 0; j < 4; ++j) {
        int c = colbase + wc * 64 + j * 16 + lr;
        float bv = (flags & FLAG_BIAS) ? bias[c] : 0.f;
#pragma unroll
        for (int i = 0; i < 4; ++i) {
            int r0 = rowbase + wr * 64 + i * 16 + rq;
#pragma unroll
            for (int t = 0; t < 4; ++t) {
                int r = r0 + t;
                if (r >= M) continue;
                float v = acc[i][j][t] + bv;
                if (flags & FLAG_RELU) v = fmaxf(v, 0.f);
                Cb[(size_t)r * ldc + c] = f2b(v);
            }
        }
    }
}

// zl[i] = s0[i] @ wl, z[i] = s0[i] @ wr  (256 -> 2 each); one wave per node
__global__ void zproj_kernel(const ushort_t* __restrict__ s0,
                             const float* __restrict__ wl, const float* __restrict__ wr,
                             float2* __restrict__ zl, float2* __restrict__ z, int M) {
    int wave = threadIdx.x >> 6;
    int lane = threadIdx.x & 63;
    int i = blockIdx.x * 4 + wave;
    if (i >= M) return;
    float l0 = 0.f, l1 = 0.f, r0 = 0.f, r1 = 0.f;
    for (int k = lane; k < 256; k += 64) {
        float hv = b2f(s0[(size_t)i * 256 + k]);
        float2 wlv = *(const float2*)&wl[2 * k];
        float2 wrv = *(const float2*)&wr[2 * k];
        l0 += hv * wlv.x; l1 += hv * wlv.y;
        r0 += hv * wrv.x; r1 += hv * wrv.y;
    }
#pragma unroll
    for (int off = 32; off > 0; off >>= 1) {
        l0 += __shfl_down(l0, off);
        l1 += __shfl_down(l1, off);
        r0 += __shfl_down(r0, off);
        r1 += __shfl_down(r1, off);
    }
    if (lane == 0) {
        zl[i] = make_float2(l0, l1);
        z[i] = make_float2(r0, r1);
    }
}

// out[i] = zl[i] + invdeg[i] * sum_nbr z[j] + b ; one thread per node
__global__ void aggz_kernel(const float2* __restrict__ z, const float2* __restrict__ zl,
                            const int* __restrict__ rowptr, const int* __restrict__ col,
                            const float* __restrict__ invdeg, const float* __restrict__ b,
                            float* __restrict__ out, int Nn) {
    int i = blockIdx.x * blockDim.x + threadIdx.x;
    if (i >= Nn) return;
    float s0 = 0.f, s1 = 0.f;
    int p = rowptr[i], p1 = rowptr[i + 1];
    for (; p + 4 <= p1; p += 4) {
        float2 a = z[col[p]], c = z[col[p + 1]], d = z[col[p + 2]], e = z[col[p + 3]];
        s0 += (a.x + c.x) + (d.x + e.x);
        s1 += (a.y + c.y) + (d.y + e.y);
    }
    for (; p < p1; ++p) {
        float2 a = z[col[p]];
        s0 += a.x; s1 += a.y;
    }
    float inv = invdeg[i];
    float2 l = zl[i];
    out[(size_t)i * 2 + 0] = l.x + inv * s0 + b[0];
    out[(size_t)i * 2 + 1] = l.y + inv * s1 + b[1];
}

extern "C" void kernel_launch(void* const* d_in, const int* in_sizes, int n_in,
                              void* d_out, int out_size, void* d_ws, size_t ws_size,
                              hipStream_t stream) {
    const float* x      = (const float*)d_in[0];
    const int*   ei     = (const int*)d_in[1];
    const float* g_w1[3] = {(const float*)d_in[2], (const float*)d_in[6],  (const float*)d_in[10]};
    const float* g_b1[3] = {(const float*)d_in[3], (const float*)d_in[7],  (const float*)d_in[11]};
    const float* g_w2[3] = {(const float*)d_in[4], (const float*)d_in[8],  (const float*)d_in[12]};
    const float* g_b2[3] = {(const float*)d_in[5], (const float*)d_in[9],  (const float*)d_in[13]};
    const float* gout_w = (const float*)d_in[14];
    const float* gout_b = (const float*)d_in[15];
    const float* s0_wl  = (const float*)d_in[16];
    const float* s0_wr  = (const float*)d_in[17];
    const float* s0_b   = (const float*)d_in[18];
    const float* s1_wl  = (const float*)d_in[19];
    const float* s1_wr  = (const float*)d_in[20];
    const float* s1_b   = (const float*)d_in[21];
    float* out = (float*)d_out;

    const int N = in_sizes[0] / 64;
    const int E = in_sizes[1] / 2;

    char* ws = (char*)d_ws;
    size_t o = 0;
    auto take = [&](size_t bytes) -> char* {
        char* p = ws + o;
        o = (o + bytes + 255) & ~(size_t)255;
        return p;
    };
    ushort_t* xb     = (ushort_t*)take((size_t)N * 64 * 2);
    ushort_t* bA     = (ushort_t*)take((size_t)N * 128 * 2);
    ushort_t* bB     = (ushort_t*)take((size_t)N * 128 * 2);
    ushort_t* bC     = (ushort_t*)take((size_t)N * 128 * 2);
    ushort_t* ginb   = (ushort_t*)take((size_t)N * 128 * 2);
    ushort_t* aggxb  = (ushort_t*)take((size_t)N * 64 * 2);
    ushort_t* agggb  = (ushort_t*)take((size_t)N * 128 * 2);
    ushort_t* s0b    = (ushort_t*)take((size_t)N * 256 * 2);
    float2*   zlb    = (float2*)take((size_t)N * 2 * 4);
    float2*   zb     = (float2*)take((size_t)N * 2 * 4);
    // transposed bf16 weights
    ushort_t* w1t0 = (ushort_t*)take(128 * 32 * 2);
    ushort_t* w2t0 = (ushort_t*)take(128 * 128 * 2);
    ushort_t* w1t1 = (ushort_t*)take(128 * 128 * 2);
    ushort_t* w2t1 = (ushort_t*)take(128 * 128 * 2);
    ushort_t* w1t2 = (ushort_t*)take(128 * 128 * 2);
    ushort_t* w2t2 = (ushort_t*)take(128 * 128 * 2);
    ushort_t* goutt = (ushort_t*)take(128 * 128 * 2);
    ushort_t* wltop = (ushort_t*)take(256 * 64 * 2);
    ushort_t* wlbot = (ushort_t*)take(256 * 128 * 2);
    ushort_t* wrtop = (ushort_t*)take(256 * 64 * 2);
    ushort_t* wrbot = (ushort_t*)take(256 * 128 * 2);
    int*   srcI   = (int*)take((size_t)E * 4);
    int*   dstI   = (int*)take((size_t)E * 4);
    int*   colI   = (int*)take((size_t)E * 4);
    int*   rowptr = (int*)take((size_t)(N + 1) * 4);
    int*   cursor = (int*)take((size_t)N * 4);
    int*   deg    = (int*)take((size_t)N * 4);
    float* invdeg = (float*)take((size_t)N * 4);
    int*   blocksum = (int*)take(256 * 4);
    int*   blockoff = (int*)take(256 * 4);
    int*   flag   = (int*)take(4);

    hipMemsetAsync(deg, 0, (size_t)N * 4, stream);
    hipMemsetAsync(flag, 1, 4, stream);

    const int TB = 256;
    const int nb = (N + 2047) / 2048;   // scan blocks (<=256)

    // --- CSR by dst ---
    detect_kernel<<<4, TB, 0, stream>>>(ei, 1024, flag);
    convert_kernel<<<(E + TB - 1) / TB, TB, 0, stream>>>(ei, E, flag, srcI, dstI);
    deg_kernel<<<(E + TB - 1) / TB, TB, 0, stream>>>(dstI, E, deg);
    scanA_kernel<<<nb, 256, 0, stream>>>(deg, N, rowptr, blocksum);
    scanB_kernel<<<1, 256, 0, stream>>>(blocksum, nb, blockoff, rowptr, N);
    scanC_kernel<<<(N + TB - 1) / TB, TB, 0, stream>>>(deg, N, blockoff, rowptr, cursor, invdeg);
    scatter_kernel<<<(E + TB - 1) / TB, TB, 0, stream>>>(srcI, dstI, E, cursor, colI);

    // --- weight convert+transpose ---
    WtArgs wa;
    const float* wsrc[11] = {g_w1[0], g_w2[0], g_w1[1], g_w2[1], g_w1[2], g_w2[2], gout_w,
                             s0_wl, s0_wl + 64 * 256, s0_wr, s0_wr + 64 * 256};
    ushort_t* wdst[11]    = {w1t0, w2t0, w1t1, w2t1, w1t2, w2t2, goutt,
                             wltop, wlbot, wrtop, wrbot};
    int wk[11] = {32, 128, 128, 128, 128, 128, 128, 64, 128, 64, 128};
    int wn[11] = {128, 128, 128, 128, 128, 128, 128, 256, 256, 256, 256};
    int base = 0;
    for (int i = 0; i < 11; ++i) {
        wa.d[i].src = wsrc[i]; wa.d[i].dst = wdst[i];
        wa.d[i].K = wk[i]; wa.d[i].N = wn[i]; wa.d[i].base = base;
        base += wk[i] * wn[i];
    }
    wa.total = base;
    wtconv_kernel<<<(base + TB - 1) / TB, TB, 0, stream>>>(wa);

    // --- x -> bf16 ---
    xconv_kernel<<<((N * 16) + TB - 1) / TB, TB, 0, stream>>>(x, xb, N * 16);

    auto gemm1 = [&](const ushort_t* A, int lda, const ushort_t* W, int K, int Nc,
                     const float* bias, ushort_t* C, int ldc, int flags) {
        GArgs ga;
        ga.p[0] = {A, W, lda, K};
        ga.np = 1;
        dim3 grid((N + 127) / 128, Nc / 128);
        mgemm_kernel<<<grid, 256, 0, stream>>>(ga, N, Nc, bias, C, ldc, flags);
    };
    const int AGG_GRID = (N + 3) / 4;

    // --- GIN layer 0 (32 -> 128): m = x[:, :32] + agg(x[:, :32]) ---
    aggb_kernel<1, 0><<<AGG_GRID, 256, 0, stream>>>(xb, 64, rowptr, colI, invdeg, bB, 32, N, 32);
    gemm1(bB, 32, w1t0, 32, 128, g_b1[0], bC, 128, FLAG_BIAS | FLAG_RELU);
    gemm1(bC, 128, w2t0, 128, 128, g_b2[0], bA, 128, FLAG_BIAS | FLAG_RELU);

    // --- GIN layers 1,2 (C=128) ---
    ushort_t* w1s[3] = {w1t0, w1t1, w1t2};
    ushort_t* w2s[3] = {w2t0, w2t1, w2t2};
    for (int l = 1; l < 3; ++l) {
        aggb_kernel<2, 0><<<AGG_GRID, 256, 0, stream>>>(bA, 128, rowptr, colI, invdeg, bB, 128, N, 64);
        gemm1(bB, 128, w1s[l], 128, 128, g_b1[l], bC, 128, FLAG_BIAS | FLAG_RELU);
        gemm1(bC, 128, w2s[l], 128, 128, g_b2[l], bA, 128, FLAG_BIAS | FLAG_RELU);
    }

    // gin_out = h @ gout_w + gout_b   (bA -> ginb)
    gemm1(bA, 128, goutt, 128, 128, gout_b, ginb, 128, FLAG_BIAS);

    // mean1 halves: aggx = mean-agg(xb) (64), aggg = mean-agg(ginb) (128)
    aggb_kernel<1, 1><<<AGG_GRID, 256, 0, stream>>>(xb, 64, rowptr, colI, invdeg, aggxb, 64, N, 64);
    aggb_kernel<2, 1><<<AGG_GRID, 256, 0, stream>>>(ginb, 128, rowptr, colI, invdeg, agggb, 128, N, 64);

    // s0 = relu(x@wl_top + gin@wl_bot + aggx@wr_top + aggg@wr_bot + b)
    {
        GArgs ga;
        ga.p[0] = {xb, wltop, 64, 64};
        ga.p[1] = {ginb, wlbot, 128, 128};
        ga.p[2] = {aggxb, wrtop, 64, 64};
        ga.p[3] = {agggb, wrbot, 128, 128};
        ga.np = 4;
        dim3 grid((N + 127) / 128, 2);
        mgemm_kernel<<<grid, 256, 0, stream>>>(ga, N, 256, s0_b, s0b, 256, FLAG_BIAS | FLAG_RELU);
    }

    // project-then-aggregate for the final layer:
    // zl = s0 @ s1_wl, z = s0 @ s1_wr  (N x 2 each, fp32)
    zproj_kernel<<<(N + 3) / 4, 256, 0, stream>>>(s0b, s1_wl, s1_wr, zlb, zb, N);
    // out = zl + invdeg * agg(z) + b
    aggz_kernel<<<(N + TB - 1) / TB, TB, 0, stream>>>(zb, zlb, rowptr, colI, invdeg, s1_b, out, N);
}

// Round 5
// 427.766 us; speedup vs baseline: 2.5868x; 1.1422x over previous
//
#include <hip/hip_runtime.h>

// ---------------------------------------------------------------------------
// GAMLNET GNN forward, bf16 edition, R4.
// R4: chain-fused MFMA GEMM (GIN MLP double-GEMM fused in LDS; layer2 also
// absorbs gout => 3 GEMM dispatches for all of GIN), 64x128 tiles (782
// blocks, 3/CU), coalesced C-store via LDS staging.
// ---------------------------------------------------------------------------

typedef unsigned short ushort_t;
typedef __bf16 bf16x8 __attribute__((ext_vector_type(8)));
typedef float f32x4 __attribute__((ext_vector_type(4)));

__device__ __forceinline__ float b2f(unsigned int u16) {
    union { unsigned int i; float f; } v;
    v.i = u16 << 16;
    return v.f;
}
__device__ __forceinline__ unsigned short f2b(float f) {
    union { float f; unsigned int i; } v;
    v.f = f;
    unsigned int x = v.i;
    unsigned int r = (x + 0x7fffu + ((x >> 16) & 1u)) >> 16;  // RNE
    return (unsigned short)r;
}

// --- edge dtype detection: if input is int64, odd int32 words are all zero ---
__global__ void detect_kernel(const int* __restrict__ ei, int ncheck, int* flag) {
    int t = blockIdx.x * blockDim.x + threadIdx.x;
    if (t < ncheck) {
        if (ei[2 * t + 1] != 0) atomicAnd(flag, 0);
    }
}

__global__ void convert_kernel(const int* __restrict__ ei, int E, const int* __restrict__ flag,
                               int* __restrict__ src, int* __restrict__ dst) {
    int e = blockIdx.x * blockDim.x + threadIdx.x;
    if (e >= E) return;
    if (*flag) {
        src[e] = ei[2 * (size_t)e];
        dst[e] = ei[2 * ((size_t)E + e)];
    } else {
        src[e] = ei[e];
        dst[e] = ei[(size_t)E + e];
    }
}

__global__ void deg_kernel(const int* __restrict__ dst, int E, int* __restrict__ deg) {
    int e = blockIdx.x * blockDim.x + threadIdx.x;
    if (e < E) atomicAdd(&deg[dst[e]], 1);
}

// --- 3-phase multi-block exclusive scan (2048 elements per block) ---
__global__ __launch_bounds__(256) void scanA_kernel(const int* __restrict__ deg, int n,
                                                    int* __restrict__ rowptr,
                                                    int* __restrict__ blocksum) {
    __shared__ int sh[256];
    int b = blockIdx.x, tid = threadIdx.x;
    int base = b * 2048 + tid * 8;
    int v[8];
#pragma unroll
    for (int e = 0; e < 8; ++e) {
        int i = base + e;
        v[e] = (i < n) ? deg[i] : 0;
    }
    int t = 0;
#pragma unroll
    for (int e = 0; e < 8; ++e) { int x = v[e]; v[e] = t; t += x; }
    sh[tid] = t;
    __syncthreads();
    for (int off = 1; off < 256; off <<= 1) {
        int val = (tid >= off) ? sh[tid - off] : 0;
        __syncthreads();
        sh[tid] += val;
        __syncthreads();
    }
    int excl = sh[tid] - t;
#pragma unroll
    for (int e = 0; e < 8; ++e) {
        int i = base + e;
        if (i < n) rowptr[i] = excl + v[e];
    }
    if (tid == 255) blocksum[b] = sh[255];
}

__global__ __launch_bounds__(256) void scanB_kernel(const int* __restrict__ blocksum, int nb,
                                                    int* __restrict__ blockoff,
                                                    int* __restrict__ rowptr, int n) {
    __shared__ int sh[256];
    int tid = threadIdx.x;
    int v = (tid < nb) ? blocksum[tid] : 0;
    sh[tid] = v;
    __syncthreads();
    for (int off = 1; off < 256; off <<= 1) {
        int t = (tid >= off) ? sh[tid - off] : 0;
        __syncthreads();
        sh[tid] += t;
        __syncthreads();
    }
    if (tid < nb) blockoff[tid] = sh[tid] - v;
    if (tid == 255) rowptr[n] = sh[255];
}

__global__ void scanC_kernel(const int* __restrict__ deg, int n, const int* __restrict__ blockoff,
                             int* __restrict__ rowptr, int* __restrict__ cursor,
                             float* __restrict__ invdeg) {
    int i = blockIdx.x * blockDim.x + threadIdx.x;
    if (i >= n) return;
    int r = rowptr[i] + blockoff[i >> 11];
    rowptr[i] = r;
    cursor[i] = r;
    invdeg[i] = 1.0f / fmaxf((float)deg[i], 1.0f);
}

__global__ void scatter_kernel(const int* __restrict__ src, const int* __restrict__ dst, int E,
                               int* __restrict__ cursor, int* __restrict__ col) {
    int e = blockIdx.x * blockDim.x + threadIdx.x;
    if (e < E) {
        int p = atomicAdd(&cursor[dst[e]], 1);
        col[p] = src[e];
    }
}

// x (fp32, N x 64) -> xb (bf16, N x 64)
__global__ void xconv_kernel(const float* __restrict__ x, ushort_t* __restrict__ xb, int total16) {
    int idx = blockIdx.x * blockDim.x + threadIdx.x;
    if (idx >= total16) return;
    float4 v = *(const float4*)&x[(size_t)idx * 4];
    ushort4 u;
    u.x = f2b(v.x); u.y = f2b(v.y); u.z = f2b(v.z); u.w = f2b(v.w);
    *(ushort4*)&xb[(size_t)idx * 4] = u;
}

// fused weight convert+transpose: dst[n*K+k] = bf16(src[k*N+n])
struct WtDesc { const float* src; ushort_t* dst; int K; int N; int base; };
struct WtArgs { WtDesc d[11]; int total; };
__global__ void wtconv_kernel(WtArgs a) {
    int idx = blockIdx.x * blockDim.x + threadIdx.x;
    if (idx >= a.total) return;
    int s = 0;
#pragma unroll
    for (int i = 1; i < 11; ++i) if (idx >= a.d[i].base) s = i;
    int local = idx - a.d[s].base;
    int K = a.d[s].K, Nn = a.d[s].N;
    int n = local / K, k = local - n * K;
    a.d[s].dst[(size_t)n * K + k] = f2b(a.d[s].src[(size_t)k * Nn + n]);
}

// ---------------------------------------------------------------------------
// bf16 gather aggregation: one wave per node, lane handles VEC bf16.
// MODE 0: out[i] = h[i] + sum_nbr h[j]   MODE 1: out[i] = invdeg[i]*sum h[j]
// ---------------------------------------------------------------------------
template <int VEC>
__device__ __forceinline__ void ldrow(const ushort_t* p, float* t) {
    if constexpr (VEC == 1) {
        t[0] = b2f(p[0]);
    } else if constexpr (VEC == 2) {
        unsigned int v = *(const unsigned int*)p;
        t[0] = b2f(v & 0xffffu); t[1] = b2f(v >> 16);
    } else {
        uint2 v = *(const uint2*)p;
        t[0] = b2f(v.x & 0xffffu); t[1] = b2f(v.x >> 16);
        t[2] = b2f(v.y & 0xffffu); t[3] = b2f(v.y >> 16);
    }
}

template <int VEC, int MODE>
__global__ __launch_bounds__(256) void aggb_kernel(
    const ushort_t* __restrict__ h, int ldh,
    const int* __restrict__ rowptr, const int* __restrict__ col,
    const float* __restrict__ invdeg,
    ushort_t* __restrict__ out, int ldo, int Nn, int lanes) {
    int wid = blockIdx.x * 4 + ((int)threadIdx.x >> 6);
    int lane = (int)threadIdx.x & 63;
    if (wid >= Nn || lane >= lanes) return;

    const ushort_t* hb = h + (size_t)lane * VEC;
    float a[VEC];
#pragma unroll
    for (int v = 0; v < VEC; ++v) a[v] = 0.f;

    int p0 = rowptr[wid], p1 = rowptr[wid + 1];
    int p = p0;
    for (; p + 4 <= p1; p += 4) {
        int j0 = col[p], j1 = col[p + 1], j2 = col[p + 2], j3 = col[p + 3];
        float t0[VEC], t1[VEC], t2[VEC], t3[VEC];
        ldrow<VEC>(hb + (size_t)j0 * ldh, t0);
        ldrow<VEC>(hb + (size_t)j1 * ldh, t1);
        ldrow<VEC>(hb + (size_t)j2 * ldh, t2);
        ldrow<VEC>(hb + (size_t)j3 * ldh, t3);
#pragma unroll
        for (int v = 0; v < VEC; ++v) a[v] += (t0[v] + t1[v]) + (t2[v] + t3[v]);
    }
    for (; p < p1; ++p) {
        float t[VEC];
        ldrow<VEC>(hb + (size_t)col[p] * ldh, t);
#pragma unroll
        for (int v = 0; v < VEC; ++v) a[v] += t[v];
    }

    if constexpr (MODE == 0) {
        float t[VEC];
        ldrow<VEC>(hb + (size_t)wid * ldh, t);
#pragma unroll
        for (int v = 0; v < VEC; ++v) a[v] += t[v];
    } else {
        float s = invdeg[wid];
#pragma unroll
        for (int v = 0; v < VEC; ++v) a[v] *= s;
    }

    ushort_t* op = out + (size_t)wid * ldo + (size_t)lane * VEC;
    if constexpr (VEC == 1) {
        op[0] = f2b(a[0]);
    } else if constexpr (VEC == 2) {
        unsigned int v = (unsigned int)f2b(a[0]) | ((unsigned int)f2b(a[1]) << 16);
        *(unsigned int*)op = v;
    } else {
        uint2 v;
        v.x = (unsigned int)f2b(a[0]) | ((unsigned int)f2b(a[1]) << 16);
        v.y = (unsigned int)f2b(a[2]) | ((unsigned int)f2b(a[3]) << 16);
        *(uint2*)op = v;
    }
}

// ---------------------------------------------------------------------------
// Chain-fused bf16 MFMA GEMM.
// Block tile 64 rows x 128 cols, 4 waves (each 32x64 = 2x4 MFMA frags).
// GEMM1: up to 4 (A,W) passes summed, A staged from global into chunked LDS.
// chain>=2: out_i = act(in @ W_i + b_i) computed entirely from LDS (the
// epilogue writes the chunked LDS buffer that feeds the next GEMM).
// Final tile staged linearly in LDS -> coalesced uint4 global stores.
// Wt layouts pre-transposed [Nc][K].
// ---------------------------------------------------------------------------
struct GPass { const ushort_t* A; const ushort_t* W; int lda; int K; };
struct FArgs {
    GPass p[4]; int np;
    const ushort_t* W2; const ushort_t* W3;   // [128][128] each
    const float* b1; const float* b2; const float* b3;
    int relu1, relu2, relu3;
    int chain;                                 // 1..3
};

__global__ __launch_bounds__(256) void fgemm_kernel(
    FArgs fa, int M, ushort_t* __restrict__ out, int ldc) {
    __shared__ __align__(16) ushort_t Tlds[4 * 64 * 40];   // [chunk][row][40]
    __shared__ __align__(16) ushort_t Wsh[128 * 40];

    int rowbase = blockIdx.x * 64;
    int colbase = blockIdx.y * 128;
    int tid = threadIdx.x;
    int lane = tid & 63, wid = tid >> 6;
    int wr2 = wid & 1, wc2 = wid >> 1;          // wave: rows wr2*32, cols wc2*64
    int lr = lane & 15, lk = (lane >> 4) * 8, rq = (lane >> 4) * 4;

    f32x4 acc[2][4];
#pragma unroll
    for (int i = 0; i < 2; ++i)
#pragma unroll
        for (int j = 0; j < 4; ++j) acc[i][j] = (f32x4){0.f, 0.f, 0.f, 0.f};

    // ---- GEMM 1: np passes, A from global ----
    for (int q = 0; q < fa.np; ++q) {
        const ushort_t* A = fa.p[q].A;
        const ushort_t* W = fa.p[q].W;
        int lda = fa.p[q].lda, K = fa.p[q].K;
        int nch = K >> 5;
        {
            int row = tid >> 2, seg = tid & 3, gr = rowbase + row;
            for (int c = 0; c < nch; ++c) {
                uint4 va = make_uint4(0u, 0u, 0u, 0u);
                if (gr < M) va = *(const uint4*)&A[(size_t)gr * lda + c * 32 + seg * 8];
                *(uint4*)&Tlds[c * 2560 + row * 40 + seg * 8] = va;
            }
        }
        for (int c = 0; c < nch; ++c) {
#pragma unroll
            for (int s = 0; s < 2; ++s) {
                int slot = tid + 256 * s;
                int row = slot >> 2, seg = slot & 3;
                *(uint4*)&Wsh[row * 40 + seg * 8] =
                    *(const uint4*)&W[(size_t)(colbase + row) * K + c * 32 + seg * 8];
            }
            __syncthreads();
            bf16x8 af[2], bfr[4];
#pragma unroll
            for (int i = 0; i < 2; ++i)
                af[i] = *(const bf16x8*)&Tlds[c * 2560 + (wr2 * 32 + i * 16 + lr) * 40 + lk];
#pragma unroll
            for (int j = 0; j < 4; ++j)
                bfr[j] = *(const bf16x8*)&Wsh[(wc2 * 64 + j * 16 + lr) * 40 + lk];
#pragma unroll
            for (int i = 0; i < 2; ++i)
#pragma unroll
                for (int j = 0; j < 4; ++j)
                    acc[i][j] = __builtin_amdgcn_mfma_f32_16x16x32_bf16(af[i], bfr[j], acc[i][j], 0, 0, 0);
            __syncthreads();
        }
    }

    // ---- chained GEMMs from LDS ----
    for (int g = 2; g <= fa.chain; ++g) {
        const float* bprev = (g == 2) ? fa.b1 : fa.b2;
        int reluprev = (g == 2) ? fa.relu1 : fa.relu2;
        const ushort_t* W = (g == 2) ? fa.W2 : fa.W3;
        // epilogue of previous GEMM -> chunked Tlds
#pragma unroll
        for (int i = 0; i < 2; ++i)
#pragma unroll
            for (int j = 0; j < 4; ++j) {
                int colj = wc2 * 64 + j * 16 + lr;
                float bv = bprev[colbase + colj];
#pragma unroll
                for (int t = 0; t < 4; ++t) {
                    int row = wr2 * 32 + i * 16 + rq + t;
                    float v = acc[i][j][t] + bv;
                    if (reluprev) v = fmaxf(v, 0.f);
                    Tlds[(colj >> 5) * 2560 + row * 40 + (colj & 31)] = f2b(v);
                }
                acc[i][j] = (f32x4){0.f, 0.f, 0.f, 0.f};
            }
        __syncthreads();
        for (int c = 0; c < 4; ++c) {
#pragma unroll
            for (int s = 0; s < 2; ++s) {
                int slot = tid + 256 * s;
                int row = slot >> 2, seg = slot & 3;
                *(uint4*)&Wsh[row * 40 + seg * 8] =
                    *(const uint4*)&W[(size_t)(colbase + row) * 128 + c * 32 + seg * 8];
            }
            __syncthreads();
            bf16x8 af[2], bfr[4];
#pragma unroll
            for (int i = 0; i < 2; ++i)
                af[i] = *(const bf16x8*)&Tlds[c * 2560 + (wr2 * 32 + i * 16 + lr) * 40 + lk];
#pragma unroll
            for (int j = 0; j < 4; ++j)
                bfr[j] = *(const bf16x8*)&Wsh[(wc2 * 64 + j * 16 + lr) * 40 + lk];
#pragma unroll
            for (int i = 0; i < 2; ++i)
#pragma unroll
                for (int j = 0; j < 4; ++j)
                    acc[i][j] = __builtin_amdgcn_mfma_f32_16x16x32_bf16(af[i], bfr[j], acc[i][j], 0, 0, 0);
            __syncthreads();
        }
    }

    // ---- final epilogue: linear LDS stage -> coalesced store ----
    const float* bf_ = (fa.chain == 1) ? fa.b1 : (fa.chain == 2) ? fa.b2 : fa.b3;
    int reluf = (fa.chain == 1) ? fa.relu1 : (fa.chain == 2) ? fa.relu2 : fa.relu3;
#pragma unroll
    for (int i = 0; i < 2; ++i)
#pragma unroll
        for (int j = 0; j < 4; ++j) {
            int colj = wc2 * 64 + j * 16 + lr;
            float bv = bf_[colbase + colj];
#pragma unroll
            for (int t = 0; t < 4; ++t) {
                int row = wr2 * 32 + i * 16 + rq + t;
                float v = acc[i][j][t] + bv;
                if (reluf) v = fmaxf(v, 0.f);
                Tlds[row * 128 + colj] = f2b(v);
            }
        }
    __syncthreads();
#pragma unroll
    for (int s = 0; s < 4; ++s) {
        int u = tid + 256 * s;           // uint4 index in 64x128 tile
        int row = u >> 4, seg = u & 15;
        int gr = rowbase + row;
        if (gr < M)
            *(uint4*)&out[(size_t)gr * ldc + colbase + seg * 8] =
                *(const uint4*)&Tlds[row * 128 + seg * 8];
    }
}

// zl[i] = s0[i] @ wl, z[i] = s0[i] @ wr  (256 -> 2 each); one wave per node
__global__ void zproj_kernel(const ushort_t* __restrict__ s0,
                             const float* __restrict__ wl, const float* __restrict__ wr,
                             float2* __restrict__ zl, float2* __restrict__ z, int M) {
    int wave = threadIdx.x >> 6;
    int lane = threadIdx.x & 63;
    int i = blockIdx.x * 4 + wave;
    if (i >= M) return;
    float l0 = 0.f, l1 = 0.f, r0 = 0.f, r1 = 0.f;
    for (int k = lane; k < 256; k += 64) {
        float hv = b2f(s0[(size_t)i * 256 + k]);
        float2 wlv = *(const float2*)&wl[2 * k];
        float2 wrv = *(const float2*)&wr[2 * k];
        l0 += hv * wlv.x; l1 += hv * wlv.y;
        r0 += hv * wrv.x; r1 += hv * wrv.y;
    }
#pragma unroll
    for (int off = 32; off > 0; off >>= 1) {
        l0 += __shfl_down(l0, off);
        l1 += __shfl_down(l1, off);
        r0 += __shfl_down(r0, off);
        r1 += __shfl_down(r1, off);
    }
    if (lane == 0) {
        zl[i] = make_float2(l0, l1);
        z[i] = make_float2(r0, r1);
    }
}

// out[i] = zl[i] + invdeg[i] * sum_nbr z[j] + b ; one thread per node
__global__ void aggz_kernel(const float2* __restrict__ z, const float2* __restrict__ zl,
                            const int* __restrict__ rowptr, const int* __restrict__ col,
                            const float* __restrict__ invdeg, const float* __restrict__ b,
                            float* __restrict__ out, int Nn) {
    int i = blockIdx.x * blockDim.x + threadIdx.x;
    if (i >= Nn) return;
    float s0 = 0.f, s1 = 0.f;
    int p = rowptr[i], p1 = rowptr[i + 1];
    for (; p + 4 <= p1; p += 4) {
        float2 a = z[col[p]], c = z[col[p + 1]], d = z[col[p + 2]], e = z[col[p + 3]];
        s0 += (a.x + c.x) + (d.x + e.x);
        s1 += (a.y + c.y) + (d.y + e.y);
    }
    for (; p < p1; ++p) {
        float2 a = z[col[p]];
        s0 += a.x; s1 += a.y;
    }
    float inv = invdeg[i];
    float2 l = zl[i];
    out[(size_t)i * 2 + 0] = l.x + inv * s0 + b[0];
    out[(size_t)i * 2 + 1] = l.y + inv * s1 + b[1];
}

extern "C" void kernel_launch(void* const* d_in, const int* in_sizes, int n_in,
                              void* d_out, int out_size, void* d_ws, size_t ws_size,
                              hipStream_t stream) {
    const float* x      = (const float*)d_in[0];
    const int*   ei     = (const int*)d_in[1];
    const float* g_w1[3] = {(const float*)d_in[2], (const float*)d_in[6],  (const float*)d_in[10]};
    const float* g_b1[3] = {(const float*)d_in[3], (const float*)d_in[7],  (const float*)d_in[11]};
    const float* g_w2[3] = {(const float*)d_in[4], (const float*)d_in[8],  (const float*)d_in[12]};
    const float* g_b2[3] = {(const float*)d_in[5], (const float*)d_in[9],  (const float*)d_in[13]};
    const float* gout_w = (const float*)d_in[14];
    const float* gout_b = (const float*)d_in[15];
    const float* s0_wl  = (const float*)d_in[16];
    const float* s0_wr  = (const float*)d_in[17];
    const float* s0_b   = (const float*)d_in[18];
    const float* s1_wl  = (const float*)d_in[19];
    const float* s1_wr  = (const float*)d_in[20];
    const float* s1_b   = (const float*)d_in[21];
    float* out = (float*)d_out;

    const int N = in_sizes[0] / 64;
    const int E = in_sizes[1] / 2;

    char* ws = (char*)d_ws;
    size_t o = 0;
    auto take = [&](size_t bytes) -> char* {
        char* p = ws + o;
        o = (o + bytes + 255) & ~(size_t)255;
        return p;
    };
    ushort_t* xb     = (ushort_t*)take((size_t)N * 64 * 2);
    ushort_t* bA     = (ushort_t*)take((size_t)N * 128 * 2);
    ushort_t* bB     = (ushort_t*)take((size_t)N * 128 * 2);
    ushort_t* bC     = (ushort_t*)take((size_t)N * 128 * 2);
    ushort_t* ginb   = (ushort_t*)take((size_t)N * 128 * 2);
    ushort_t* aggxb  = (ushort_t*)take((size_t)N * 64 * 2);
    ushort_t* agggb  = (ushort_t*)take((size_t)N * 128 * 2);
    ushort_t* s0b    = (ushort_t*)take((size_t)N * 256 * 2);
    float2*   zlb    = (float2*)take((size_t)N * 2 * 4);
    float2*   zb     = (float2*)take((size_t)N * 2 * 4);
    // transposed bf16 weights
    ushort_t* w1t0 = (ushort_t*)take(128 * 32 * 2);
    ushort_t* w2t0 = (ushort_t*)take(128 * 128 * 2);
    ushort_t* w1t1 = (ushort_t*)take(128 * 128 * 2);
    ushort_t* w2t1 = (ushort_t*)take(128 * 128 * 2);
    ushort_t* w1t2 = (ushort_t*)take(128 * 128 * 2);
    ushort_t* w2t2 = (ushort_t*)take(128 * 128 * 2);
    ushort_t* goutt = (ushort_t*)take(128 * 128 * 2);
    ushort_t* wltop = (ushort_t*)take(256 * 64 * 2);
    ushort_t* wlbot = (ushort_t*)take(256 * 128 * 2);
    ushort_t* wrtop = (ushort_t*)take(256 * 64 * 2);
    ushort_t* wrbot = (ushort_t*)take(256 * 128 * 2);
    int*   srcI   = (int*)take((size_t)E * 4);
    int*   dstI   = (int*)take((size_t)E * 4);
    int*   colI   = (int*)take((size_t)E * 4);
    int*   rowptr = (int*)take((size_t)(N + 1) * 4);
    int*   cursor = (int*)take((size_t)N * 4);
    int*   deg    = (int*)take((size_t)N * 4);
    float* invdeg = (float*)take((size_t)N * 4);
    int*   blocksum = (int*)take(256 * 4);
    int*   blockoff = (int*)take(256 * 4);
    int*   flag   = (int*)take(4);

    hipMemsetAsync(deg, 0, (size_t)N * 4, stream);
    hipMemsetAsync(flag, 1, 4, stream);

    const int TB = 256;
    const int nb = (N + 2047) / 2048;

    // --- CSR by dst ---
    detect_kernel<<<4, TB, 0, stream>>>(ei, 1024, flag);
    convert_kernel<<<(E + TB - 1) / TB, TB, 0, stream>>>(ei, E, flag, srcI, dstI);
    deg_kernel<<<(E + TB - 1) / TB, TB, 0, stream>>>(dstI, E, deg);
    scanA_kernel<<<nb, 256, 0, stream>>>(deg, N, rowptr, blocksum);
    scanB_kernel<<<1, 256, 0, stream>>>(blocksum, nb, blockoff, rowptr, N);
    scanC_kernel<<<(N + TB - 1) / TB, TB, 0, stream>>>(deg, N, blockoff, rowptr, cursor, invdeg);
    scatter_kernel<<<(E + TB - 1) / TB, TB, 0, stream>>>(srcI, dstI, E, cursor, colI);

    // --- weight convert+transpose ---
    WtArgs wa;
    const float* wsrc[11] = {g_w1[0], g_w2[0], g_w1[1], g_w2[1], g_w1[2], g_w2[2], gout_w,
                             s0_wl, s0_wl + 64 * 256, s0_wr, s0_wr + 64 * 256};
    ushort_t* wdst[11]    = {w1t0, w2t0, w1t1, w2t1, w1t2, w2t2, goutt,
                             wltop, wlbot, wrtop, wrbot};
    int wk[11] = {32, 128, 128, 128, 128, 128, 128, 64, 128, 64, 128};
    int wn[11] = {128, 128, 128, 128, 128, 128, 128, 256, 256, 256, 256};
    int base = 0;
    for (int i = 0; i < 11; ++i) {
        wa.d[i].src = wsrc[i]; wa.d[i].dst = wdst[i];
        wa.d[i].K = wk[i]; wa.d[i].N = wn[i]; wa.d[i].base = base;
        base += wk[i] * wn[i];
    }
    wa.total = base;
    wtconv_kernel<<<(base + TB - 1) / TB, TB, 0, stream>>>(wa);

    // --- x -> bf16 ---
    xconv_kernel<<<((N * 16) + TB - 1) / TB, TB, 0, stream>>>(x, xb, N * 16);

    const int AGG_GRID = (N + 3) / 4;
    const int GX = (N + 63) / 64;

    // --- GIN layer 0: m0 = x[:,:32] + agg (32-wide) -> h1 = bA ---
    aggb_kernel<1, 0><<<AGG_GRID, 256, 0, stream>>>(xb, 64, rowptr, colI, invdeg, bB, 32, N, 32);
    {
        FArgs fa = {};
        fa.p[0] = {bB, w1t0, 32, 32};
        fa.np = 1;
        fa.W2 = w2t0;
        fa.b1 = g_b1[0]; fa.b2 = g_b2[0];
        fa.relu1 = 1; fa.relu2 = 1;
        fa.chain = 2;
        fgemm_kernel<<<dim3(GX, 1), 256, 0, stream>>>(fa, N, bA, 128);
    }

    // --- GIN layer 1: bA -> agg bB -> h2 = bC ---
    aggb_kernel<2, 0><<<AGG_GRID, 256, 0, stream>>>(bA, 128, rowptr, colI, invdeg, bB, 128, N, 64);
    {
        FArgs fa = {};
        fa.p[0] = {bB, w1t1, 128, 128};
        fa.np = 1;
        fa.W2 = w2t1;
        fa.b1 = g_b1[1]; fa.b2 = g_b2[1];
        fa.relu1 = 1; fa.relu2 = 1;
        fa.chain = 2;
        fgemm_kernel<<<dim3(GX, 1), 256, 0, stream>>>(fa, N, bC, 128);
    }

    // --- GIN layer 2 + gout: bC -> agg bB -> gin = ginb (chain=3) ---
    aggb_kernel<2, 0><<<AGG_GRID, 256, 0, stream>>>(bC, 128, rowptr, colI, invdeg, bB, 128, N, 64);
    {
        FArgs fa = {};
        fa.p[0] = {bB, w1t2, 128, 128};
        fa.np = 1;
        fa.W2 = w2t2; fa.W3 = goutt;
        fa.b1 = g_b1[2]; fa.b2 = g_b2[2]; fa.b3 = gout_b;
        fa.relu1 = 1; fa.relu2 = 1; fa.relu3 = 0;
        fa.chain = 3;
        fgemm_kernel<<<dim3(GX, 1), 256, 0, stream>>>(fa, N, ginb, 128);
    }

    // mean1 halves: aggx = mean-agg(xb) (64), aggg = mean-agg(ginb) (128)
    aggb_kernel<1, 1><<<AGG_GRID, 256, 0, stream>>>(xb, 64, rowptr, colI, invdeg, aggxb, 64, N, 64);
    aggb_kernel<2, 1><<<AGG_GRID, 256, 0, stream>>>(ginb, 128, rowptr, colI, invdeg, agggb, 128, N, 64);

    // s0 = relu(x@wl_top + gin@wl_bot + aggx@wr_top + aggg@wr_bot + b) (Nc=256)
    {
        FArgs fa = {};
        fa.p[0] = {xb, wltop, 64, 64};
        fa.p[1] = {ginb, wlbot, 128, 128};
        fa.p[2] = {aggxb, wrtop, 64, 64};
        fa.p[3] = {agggb, wrbot, 128, 128};
        fa.np = 4;
        fa.b1 = s0_b;
        fa.relu1 = 1;
        fa.chain = 1;
        fgemm_kernel<<<dim3(GX, 2), 256, 0, stream>>>(fa, N, s0b, 256);
    }

    // project-then-aggregate for the final layer
    zproj_kernel<<<(N + 3) / 4, 256, 0, stream>>>(s0b, s1_wl, s1_wr, zlb, zb, N);
    aggz_kernel<<<(N + TB - 1) / TB, TB, 0, stream>>>(zb, zlb, rowptr, colI, invdeg, s1_b, out, N);
}

// Round 6
// 381.499 us; speedup vs baseline: 2.9005x; 1.1213x over previous
//
#include <hip/hip_runtime.h>

// ---------------------------------------------------------------------------
// GAMLNET GNN forward, bf16 edition, R5.
// R5: W pre-packed into per-lane MFMA fragment order (coalesced L2 reads, no
// LDS W staging, ~5 barriers/dispatch), 512-thread fgemm blocks (16 waves/CU),
// merged x-gather (GIN-0 input + mean1-x in one pass).
// ---------------------------------------------------------------------------

typedef unsigned short ushort_t;
typedef __bf16 bf16x8 __attribute__((ext_vector_type(8)));
typedef float f32x4 __attribute__((ext_vector_type(4)));

__device__ __forceinline__ float b2f(unsigned int u16) {
    union { unsigned int i; float f; } v;
    v.i = u16 << 16;
    return v.f;
}
__device__ __forceinline__ unsigned short f2b(float f) {
    union { float f; unsigned int i; } v;
    v.f = f;
    unsigned int x = v.i;
    unsigned int r = (x + 0x7fffu + ((x >> 16) & 1u)) >> 16;  // RNE
    return (unsigned short)r;
}

// --- edge dtype detection: if input is int64, odd int32 words are all zero ---
__global__ void detect_kernel(const int* __restrict__ ei, int ncheck, int* flag) {
    int t = blockIdx.x * blockDim.x + threadIdx.x;
    if (t < ncheck) {
        if (ei[2 * t + 1] != 0) atomicAnd(flag, 0);
    }
}

__global__ void convert_kernel(const int* __restrict__ ei, int E, const int* __restrict__ flag,
                               int* __restrict__ src, int* __restrict__ dst) {
    int e = blockIdx.x * blockDim.x + threadIdx.x;
    if (e >= E) return;
    if (*flag) {
        src[e] = ei[2 * (size_t)e];
        dst[e] = ei[2 * ((size_t)E + e)];
    } else {
        src[e] = ei[e];
        dst[e] = ei[(size_t)E + e];
    }
}

__global__ void deg_kernel(const int* __restrict__ dst, int E, int* __restrict__ deg) {
    int e = blockIdx.x * blockDim.x + threadIdx.x;
    if (e < E) atomicAdd(&deg[dst[e]], 1);
}

// --- 3-phase multi-block exclusive scan (2048 elements per block) ---
__global__ __launch_bounds__(256) void scanA_kernel(const int* __restrict__ deg, int n,
                                                    int* __restrict__ rowptr,
                                                    int* __restrict__ blocksum) {
    __shared__ int sh[256];
    int b = blockIdx.x, tid = threadIdx.x;
    int base = b * 2048 + tid * 8;
    int v[8];
#pragma unroll
    for (int e = 0; e < 8; ++e) {
        int i = base + e;
        v[e] = (i < n) ? deg[i] : 0;
    }
    int t = 0;
#pragma unroll
    for (int e = 0; e < 8; ++e) { int x = v[e]; v[e] = t; t += x; }
    sh[tid] = t;
    __syncthreads();
    for (int off = 1; off < 256; off <<= 1) {
        int val = (tid >= off) ? sh[tid - off] : 0;
        __syncthreads();
        sh[tid] += val;
        __syncthreads();
    }
    int excl = sh[tid] - t;
#pragma unroll
    for (int e = 0; e < 8; ++e) {
        int i = base + e;
        if (i < n) rowptr[i] = excl + v[e];
    }
    if (tid == 255) blocksum[b] = sh[255];
}

__global__ __launch_bounds__(256) void scanB_kernel(const int* __restrict__ blocksum, int nb,
                                                    int* __restrict__ blockoff,
                                                    int* __restrict__ rowptr, int n) {
    __shared__ int sh[256];
    int tid = threadIdx.x;
    int v = (tid < nb) ? blocksum[tid] : 0;
    sh[tid] = v;
    __syncthreads();
    for (int off = 1; off < 256; off <<= 1) {
        int t = (tid >= off) ? sh[tid - off] : 0;
        __syncthreads();
        sh[tid] += t;
        __syncthreads();
    }
    if (tid < nb) blockoff[tid] = sh[tid] - v;
    if (tid == 255) rowptr[n] = sh[255];
}

__global__ void scanC_kernel(const int* __restrict__ deg, int n, const int* __restrict__ blockoff,
                             int* __restrict__ rowptr, int* __restrict__ cursor,
                             float* __restrict__ invdeg) {
    int i = blockIdx.x * blockDim.x + threadIdx.x;
    if (i >= n) return;
    int r = rowptr[i] + blockoff[i >> 11];
    rowptr[i] = r;
    cursor[i] = r;
    invdeg[i] = 1.0f / fmaxf((float)deg[i], 1.0f);
}

__global__ void scatter_kernel(const int* __restrict__ src, const int* __restrict__ dst, int E,
                               int* __restrict__ cursor, int* __restrict__ col) {
    int e = blockIdx.x * blockDim.x + threadIdx.x;
    if (e < E) {
        int p = atomicAdd(&cursor[dst[e]], 1);
        col[p] = src[e];
    }
}

// x (fp32, N x 64) -> xb (bf16, N x 64)
__global__ void xconv_kernel(const float* __restrict__ x, ushort_t* __restrict__ xb, int total16) {
    int idx = blockIdx.x * blockDim.x + threadIdx.x;
    if (idx >= total16) return;
    float4 v = *(const float4*)&x[(size_t)idx * 4];
    ushort4 u;
    u.x = f2b(v.x); u.y = f2b(v.y); u.z = f2b(v.z); u.w = f2b(v.w);
    *(ushort4*)&xb[(size_t)idx * 4] = u;
}

// ---------------------------------------------------------------------------
// Weight convert + pack into MFMA fragment order.
// Source: fp32 [K][N] (row k, col n). Packed dst (bf16):
// off = ((n>>4)*(K>>5) + (k>>5))*512 + ((n&15)|(((k>>3)&3)<<4))*8 + (k&7)
// so that frag(cg, c) for lane l is dst[(cg*(K/32)+c)*512 + l*8 .. +8].
// ---------------------------------------------------------------------------
struct WtDesc { const float* src; ushort_t* dst; int lk2; int K; int N; int base; };
struct WtArgs { WtDesc d[11]; int total; };
__global__ void wtconv_kernel(WtArgs a) {
    int idx = blockIdx.x * blockDim.x + threadIdx.x;
    if (idx >= a.total) return;
    int s = 0;
#pragma unroll
    for (int i = 1; i < 11; ++i) if (idx >= a.d[i].base) s = i;
    int local = idx - a.d[s].base;
    int K = a.d[s].K;
    int n = local >> a.d[s].lk2;
    int k = local & (K - 1);
    unsigned off = (unsigned)((n >> 4) * (K >> 5) + (k >> 5)) * 512u
                 + (unsigned)(((n & 15) | (((k >> 3) & 3) << 4)) << 3) + (unsigned)(k & 7);
    a.d[s].dst[off] = f2b(a.d[s].src[(size_t)k * a.d[s].N + n]);
}

// ---------------------------------------------------------------------------
// bf16 gather aggregation: one wave per node, lane handles VEC bf16.
// MODE 0: out[i] = h[i] + sum_nbr h[j]   MODE 1: out[i] = invdeg[i]*sum h[j]
// ---------------------------------------------------------------------------
template <int VEC>
__device__ __forceinline__ void ldrow(const ushort_t* p, float* t) {
    if constexpr (VEC == 1) {
        t[0] = b2f(p[0]);
    } else if constexpr (VEC == 2) {
        unsigned int v = *(const unsigned int*)p;
        t[0] = b2f(v & 0xffffu); t[1] = b2f(v >> 16);
    } else {
        uint2 v = *(const uint2*)p;
        t[0] = b2f(v.x & 0xffffu); t[1] = b2f(v.x >> 16);
        t[2] = b2f(v.y & 0xffffu); t[3] = b2f(v.y >> 16);
    }
}

template <int VEC, int MODE>
__global__ __launch_bounds__(256) void aggb_kernel(
    const ushort_t* __restrict__ h, int ldh,
    const int* __restrict__ rowptr, const int* __restrict__ col,
    const float* __restrict__ invdeg,
    ushort_t* __restrict__ out, int ldo, int Nn, int lanes) {
    int wid = blockIdx.x * 4 + ((int)threadIdx.x >> 6);
    int lane = (int)threadIdx.x & 63;
    if (wid >= Nn || lane >= lanes) return;

    const ushort_t* hb = h + (size_t)lane * VEC;
    float a[VEC];
#pragma unroll
    for (int v = 0; v < VEC; ++v) a[v] = 0.f;

    int p0 = rowptr[wid], p1 = rowptr[wid + 1];
    int p = p0;
    for (; p + 4 <= p1; p += 4) {
        int j0 = col[p], j1 = col[p + 1], j2 = col[p + 2], j3 = col[p + 3];
        float t0[VEC], t1[VEC], t2[VEC], t3[VEC];
        ldrow<VEC>(hb + (size_t)j0 * ldh, t0);
        ldrow<VEC>(hb + (size_t)j1 * ldh, t1);
        ldrow<VEC>(hb + (size_t)j2 * ldh, t2);
        ldrow<VEC>(hb + (size_t)j3 * ldh, t3);
#pragma unroll
        for (int v = 0; v < VEC; ++v) a[v] += (t0[v] + t1[v]) + (t2[v] + t3[v]);
    }
    for (; p < p1; ++p) {
        float t[VEC];
        ldrow<VEC>(hb + (size_t)col[p] * ldh, t);
#pragma unroll
        for (int v = 0; v < VEC; ++v) a[v] += t[v];
    }

    if constexpr (MODE == 0) {
        float t[VEC];
        ldrow<VEC>(hb + (size_t)wid * ldh, t);
#pragma unroll
        for (int v = 0; v < VEC; ++v) a[v] += t[v];
    } else {
        float s = invdeg[wid];
#pragma unroll
        for (int v = 0; v < VEC; ++v) a[v] *= s;
    }

    ushort_t* op = out + (size_t)wid * ldo + (size_t)lane * VEC;
    if constexpr (VEC == 1) {
        op[0] = f2b(a[0]);
    } else if constexpr (VEC == 2) {
        unsigned int v = (unsigned int)f2b(a[0]) | ((unsigned int)f2b(a[1]) << 16);
        *(unsigned int*)op = v;
    } else {
        uint2 v;
        v.x = (unsigned int)f2b(a[0]) | ((unsigned int)f2b(a[1]) << 16);
        v.y = (unsigned int)f2b(a[2]) | ((unsigned int)f2b(a[3]) << 16);
        *(uint2*)op = v;
    }
}

// Merged x-gather: one 64-wide sum-gather of xb produces BOTH
// out32[i] = x[i,:32] + sum_nbr x[j,:32]  (GIN-0 input) AND
// out64[i] = invdeg[i] * sum_nbr x[j,:64] (mean1 x-half).
__global__ __launch_bounds__(256) void aggdual_kernel(
    const ushort_t* __restrict__ xb,
    const int* __restrict__ rowptr, const int* __restrict__ col,
    const float* __restrict__ invdeg,
    ushort_t* __restrict__ out32, ushort_t* __restrict__ out64, int Nn) {
    int wid = blockIdx.x * 4 + ((int)threadIdx.x >> 6);
    int lane = (int)threadIdx.x & 63;
    if (wid >= Nn) return;
    const ushort_t* hb = xb + lane;
    float a = 0.f;
    int p = rowptr[wid], p1 = rowptr[wid + 1];
    for (; p + 4 <= p1; p += 4) {
        float v0 = b2f(hb[(size_t)col[p] * 64]);
        float v1 = b2f(hb[(size_t)col[p + 1] * 64]);
        float v2 = b2f(hb[(size_t)col[p + 2] * 64]);
        float v3 = b2f(hb[(size_t)col[p + 3] * 64]);
        a += (v0 + v1) + (v2 + v3);
    }
    for (; p < p1; ++p) a += b2f(hb[(size_t)col[p] * 64]);
    out64[(size_t)wid * 64 + lane] = f2b(a * invdeg[wid]);
    if (lane < 32) {
        float self = b2f(hb[(size_t)wid * 64]);
        out32[(size_t)wid * 32 + lane] = f2b(a + self);
    }
}

// ---------------------------------------------------------------------------
// Chain-fused bf16 MFMA GEMM, R5 schedule.
// Block: 512 threads (8 waves), tile 64 rows x 128 cols; wave = 16 rows x 64
// cols (1x4 frags). A staged once per pass into chunked LDS; W read directly
// from L2 in pre-packed fragment order (coalesced 16B/lane). ~5 barriers per
// dispatch. chain>=2 runs extra 128x128 GEMMs entirely from LDS.
// ---------------------------------------------------------------------------
struct GPass { const ushort_t* A; const ushort_t* Wp; int lda; int K; };
struct FArgs {
    GPass p[4]; int np;
    const ushort_t* W2p; const ushort_t* W3p;   // packed, K=128, N=128
    const float* b1; const float* b2; const float* b3;
    int relu1, relu2, relu3;
    int chain;                                   // 1..3
};

__global__ __launch_bounds__(512) void fgemm_kernel(
    FArgs fa, int M, ushort_t* __restrict__ out, int ldc) {
    __shared__ __align__(16) ushort_t Tlds[4 * 64 * 40];   // 20 KB

    int rowbase = blockIdx.x * 64;
    int colbase = blockIdx.y * 128;
    int tid = threadIdx.x;
    int lane = tid & 63, wid = tid >> 6;
    int wr3 = wid & 3, wc2 = wid >> 2;          // wave: rows wr3*16, cols wc2*64
    int lr = lane & 15, lk = (lane >> 4) * 8, rq = (lane >> 4) * 4;

    f32x4 acc[4];
#pragma unroll
    for (int j = 0; j < 4; ++j) acc[j] = (f32x4){0.f, 0.f, 0.f, 0.f};

    // ---- GEMM 1: np passes, A from global, W from packed global (L2) ----
    for (int q = 0; q < fa.np; ++q) {
        const ushort_t* A = fa.p[q].A;
        const ushort_t* Wp = fa.p[q].Wp;
        int lda = fa.p[q].lda, K = fa.p[q].K;
        int nch = K >> 5;
        for (int u = tid; u < 256 * nch; u += 512) {
            int c = u >> 8, r = (u >> 2) & 63, seg = u & 3;
            int gr = rowbase + r;
            uint4 va = make_uint4(0u, 0u, 0u, 0u);
            if (gr < M) va = *(const uint4*)&A[(size_t)gr * lda + c * 32 + seg * 8];
            *(uint4*)&Tlds[c * 2560 + r * 40 + seg * 8] = va;
        }
        __syncthreads();
        int cg0 = (colbase >> 4) + wc2 * 4;
        for (int c = 0; c < nch; ++c) {
            bf16x8 af = *(const bf16x8*)&Tlds[c * 2560 + (wr3 * 16 + lr) * 40 + lk];
            bf16x8 bfr[4];
#pragma unroll
            for (int j = 0; j < 4; ++j)
                bfr[j] = *(const bf16x8*)&Wp[((size_t)(cg0 + j) * nch + c) * 512 + lane * 8];
#pragma unroll
            for (int j = 0; j < 4; ++j)
                acc[j] = __builtin_amdgcn_mfma_f32_16x16x32_bf16(af, bfr[j], acc[j], 0, 0, 0);
        }
        __syncthreads();
    }

    // ---- chained 128x128 GEMMs from LDS ----
    for (int g = 2; g <= fa.chain; ++g) {
        const float* bprev = (g == 2) ? fa.b1 : fa.b2;
        int reluprev = (g == 2) ? fa.relu1 : fa.relu2;
        const ushort_t* Wp = (g == 2) ? fa.W2p : fa.W3p;
#pragma unroll
        for (int j = 0; j < 4; ++j) {
            int colj = wc2 * 64 + j * 16 + lr;
            float bv = bprev[colj];
#pragma unroll
            for (int t = 0; t < 4; ++t) {
                int row = wr3 * 16 + rq + t;
                float v = acc[j][t] + bv;
                if (reluprev) v = fmaxf(v, 0.f);
                Tlds[(colj >> 5) * 2560 + row * 40 + (colj & 31)] = f2b(v);
            }
            acc[j] = (f32x4){0.f, 0.f, 0.f, 0.f};
        }
        __syncthreads();
        int cg0 = wc2 * 4;
        for (int c = 0; c < 4; ++c) {
            bf16x8 af = *(const bf16x8*)&Tlds[c * 2560 + (wr3 * 16 + lr) * 40 + lk];
            bf16x8 bfr[4];
#pragma unroll
            for (int j = 0; j < 4; ++j)
                bfr[j] = *(const bf16x8*)&Wp[((size_t)(cg0 + j) * 4 + c) * 512 + lane * 8];
#pragma unroll
            for (int j = 0; j < 4; ++j)
                acc[j] = __builtin_amdgcn_mfma_f32_16x16x32_bf16(af, bfr[j], acc[j], 0, 0, 0);
        }
        __syncthreads();
    }

    // ---- final epilogue: linear LDS stage -> coalesced store ----
    const float* bf_ = (fa.chain == 1) ? fa.b1 : (fa.chain == 2) ? fa.b2 : fa.b3;
    int reluf = (fa.chain == 1) ? fa.relu1 : (fa.chain == 2) ? fa.relu2 : fa.relu3;
#pragma unroll
    for (int j = 0; j < 4; ++j) {
        int colj = wc2 * 64 + j * 16 + lr;
        float bv = bf_[colbase + colj];
#pragma unroll
        for (int t = 0; t < 4; ++t) {
            int row = wr3 * 16 + rq + t;
            float v = acc[j][t] + bv;
            if (reluf) v = fmaxf(v, 0.f);
            Tlds[row * 128 + colj] = f2b(v);
        }
    }
    __syncthreads();
    for (int u = tid; u < 1024; u += 512) {
        int row = u >> 4, seg = u & 15;
        int gr = rowbase + row;
        if (gr < M)
            *(uint4*)&out[(size_t)gr * ldc + colbase + seg * 8] =
                *(const uint4*)&Tlds[row * 128 + seg * 8];
    }
}

// zl[i] = s0[i] @ wl, z[i] = s0[i] @ wr  (256 -> 2 each); one wave per node
__global__ void zproj_kernel(const ushort_t* __restrict__ s0,
                             const float* __restrict__ wl, const float* __restrict__ wr,
                             float2* __restrict__ zl, float2* __restrict__ z, int M) {
    int wave = threadIdx.x >> 6;
    int lane = threadIdx.x & 63;
    int i = blockIdx.x * 4 + wave;
    if (i >= M) return;
    float l0 = 0.f, l1 = 0.f, r0 = 0.f, r1 = 0.f;
    for (int k = lane; k < 256; k += 64) {
        float hv = b2f(s0[(size_t)i * 256 + k]);
        float2 wlv = *(const float2*)&wl[2 * k];
        float2 wrv = *(const float2*)&wr[2 * k];
        l0 += hv * wlv.x; l1 += hv * wlv.y;
        r0 += hv * wrv.x; r1 += hv * wrv.y;
    }
#pragma unroll
    for (int off = 32; off > 0; off >>= 1) {
        l0 += __shfl_down(l0, off);
        l1 += __shfl_down(l1, off);
        r0 += __shfl_down(r0, off);
        r1 += __shfl_down(r1, off);
    }
    if (lane == 0) {
        zl[i] = make_float2(l0, l1);
        z[i] = make_float2(r0, r1);
    }
}

// out[i] = zl[i] + invdeg[i] * sum_nbr z[j] + b ; one thread per node
__global__ void aggz_kernel(const float2* __restrict__ z, const float2* __restrict__ zl,
                            const int* __restrict__ rowptr, const int* __restrict__ col,
                            const float* __restrict__ invdeg, const float* __restrict__ b,
                            float* __restrict__ out, int Nn) {
    int i = blockIdx.x * blockDim.x + threadIdx.x;
    if (i >= Nn) return;
    float s0 = 0.f, s1 = 0.f;
    int p = rowptr[i], p1 = rowptr[i + 1];
    for (; p + 4 <= p1; p += 4) {
        float2 a = z[col[p]], c = z[col[p + 1]], d = z[col[p + 2]], e = z[col[p + 3]];
        s0 += (a.x + c.x) + (d.x + e.x);
        s1 += (a.y + c.y) + (d.y + e.y);
    }
    for (; p < p1; ++p) {
        float2 a = z[col[p]];
        s0 += a.x; s1 += a.y;
    }
    float inv = invdeg[i];
    float2 l = zl[i];
    out[(size_t)i * 2 + 0] = l.x + inv * s0 + b[0];
    out[(size_t)i * 2 + 1] = l.y + inv * s1 + b[1];
}

extern "C" void kernel_launch(void* const* d_in, const int* in_sizes, int n_in,
                              void* d_out, int out_size, void* d_ws, size_t ws_size,
                              hipStream_t stream) {
    const float* x      = (const float*)d_in[0];
    const int*   ei     = (const int*)d_in[1];
    const float* g_w1[3] = {(const float*)d_in[2], (const float*)d_in[6],  (const float*)d_in[10]};
    const float* g_b1[3] = {(const float*)d_in[3], (const float*)d_in[7],  (const float*)d_in[11]};
    const float* g_w2[3] = {(const float*)d_in[4], (const float*)d_in[8],  (const float*)d_in[12]};
    const float* g_b2[3] = {(const float*)d_in[5], (const float*)d_in[9],  (const float*)d_in[13]};
    const float* gout_w = (const float*)d_in[14];
    const float* gout_b = (const float*)d_in[15];
    const float* s0_wl  = (const float*)d_in[16];
    const float* s0_wr  = (const float*)d_in[17];
    const float* s0_b   = (const float*)d_in[18];
    const float* s1_wl  = (const float*)d_in[19];
    const float* s1_wr  = (const float*)d_in[20];
    const float* s1_b   = (const float*)d_in[21];
    float* out = (float*)d_out;

    const int N = in_sizes[0] / 64;
    const int E = in_sizes[1] / 2;

    char* ws = (char*)d_ws;
    size_t o = 0;
    auto take = [&](size_t bytes) -> char* {
        char* p = ws + o;
        o = (o + bytes + 255) & ~(size_t)255;
        return p;
    };
    ushort_t* xb     = (ushort_t*)take((size_t)N * 64 * 2);
    ushort_t* bA     = (ushort_t*)take((size_t)N * 128 * 2);
    ushort_t* bB     = (ushort_t*)take((size_t)N * 128 * 2);
    ushort_t* bC     = (ushort_t*)take((size_t)N * 128 * 2);
    ushort_t* ginb   = (ushort_t*)take((size_t)N * 128 * 2);
    ushort_t* aggxb  = (ushort_t*)take((size_t)N * 64 * 2);
    ushort_t* agggb  = (ushort_t*)take((size_t)N * 128 * 2);
    ushort_t* s0b    = (ushort_t*)take((size_t)N * 256 * 2);
    float2*   zlb    = (float2*)take((size_t)N * 2 * 4);
    float2*   zb     = (float2*)take((size_t)N * 2 * 4);
    // packed bf16 weights (fragment order)
    ushort_t* w1t0 = (ushort_t*)take(128 * 32 * 2);
    ushort_t* w2t0 = (ushort_t*)take(128 * 128 * 2);
    ushort_t* w1t1 = (ushort_t*)take(128 * 128 * 2);
    ushort_t* w2t1 = (ushort_t*)take(128 * 128 * 2);
    ushort_t* w1t2 = (ushort_t*)take(128 * 128 * 2);
    ushort_t* w2t2 = (ushort_t*)take(128 * 128 * 2);
    ushort_t* goutt = (ushort_t*)take(128 * 128 * 2);
    ushort_t* wltop = (ushort_t*)take(256 * 64 * 2);
    ushort_t* wlbot = (ushort_t*)take(256 * 128 * 2);
    ushort_t* wrtop = (ushort_t*)take(256 * 64 * 2);
    ushort_t* wrbot = (ushort_t*)take(256 * 128 * 2);
    int*   srcI   = (int*)take((size_t)E * 4);
    int*   dstI   = (int*)take((size_t)E * 4);
    int*   colI   = (int*)take((size_t)E * 4);
    int*   rowptr = (int*)take((size_t)(N + 1) * 4);
    int*   cursor = (int*)take((size_t)N * 4);
    int*   deg    = (int*)take((size_t)N * 4);
    float* invdeg = (float*)take((size_t)N * 4);
    int*   blocksum = (int*)take(256 * 4);
    int*   blockoff = (int*)take(256 * 4);
    int*   flag   = (int*)take(4);

    hipMemsetAsync(deg, 0, (size_t)N * 4, stream);
    hipMemsetAsync(flag, 1, 4, stream);

    const int TB = 256;
    const int nb = (N + 2047) / 2048;

    // --- CSR by dst ---
    detect_kernel<<<4, TB, 0, stream>>>(ei, 1024, flag);
    convert_kernel<<<(E + TB - 1) / TB, TB, 0, stream>>>(ei, E, flag, srcI, dstI);
    deg_kernel<<<(E + TB - 1) / TB, TB, 0, stream>>>(dstI, E, deg);
    scanA_kernel<<<nb, 256, 0, stream>>>(deg, N, rowptr, blocksum);
    scanB_kernel<<<1, 256, 0, stream>>>(blocksum, nb, blockoff, rowptr, N);
    scanC_kernel<<<(N + TB - 1) / TB, TB, 0, stream>>>(deg, N, blockoff, rowptr, cursor, invdeg);
    scatter_kernel<<<(E + TB - 1) / TB, TB, 0, stream>>>(srcI, dstI, E, cursor, colI);

    // --- weight convert+pack ---
    WtArgs wa;
    const float* wsrc[11] = {g_w1[0], g_w2[0], g_w1[1], g_w2[1], g_w1[2], g_w2[2], gout_w,
                             s0_wl, s0_wl + 64 * 256, s0_wr, s0_wr + 64 * 256};
    ushort_t* wdst[11]    = {w1t0, w2t0, w1t1, w2t1, w1t2, w2t2, goutt,
                             wltop, wlbot, wrtop, wrbot};
    int wk[11]  = {32, 128, 128, 128, 128, 128, 128, 64, 128, 64, 128};
    int wl2[11] = {5, 7, 7, 7, 7, 7, 7, 6, 7, 6, 7};
    int wn[11]  = {128, 128, 128, 128, 128, 128, 128, 256, 256, 256, 256};
    int base = 0;
    for (int i = 0; i < 11; ++i) {
        wa.d[i].src = wsrc[i]; wa.d[i].dst = wdst[i];
        wa.d[i].lk2 = wl2[i]; wa.d[i].K = wk[i]; wa.d[i].N = wn[i]; wa.d[i].base = base;
        base += wk[i] * wn[i];
    }
    wa.total = base;
    wtconv_kernel<<<(base + TB - 1) / TB, TB, 0, stream>>>(wa);

    // --- x -> bf16 ---
    xconv_kernel<<<((N * 16) + TB - 1) / TB, TB, 0, stream>>>(x, xb, N * 16);

    const int AGG_GRID = (N + 3) / 4;
    const int GX = (N + 63) / 64;

    // merged x-gather: bB = GIN-0 input (32-wide), aggxb = mean1-x (64-wide)
    aggdual_kernel<<<AGG_GRID, 256, 0, stream>>>(xb, rowptr, colI, invdeg, bB, aggxb, N);

    // --- GIN layer 0 (chain=2): bB -> h1 = bA ---
    {
        FArgs fa = {};
        fa.p[0] = {bB, w1t0, 32, 32};
        fa.np = 1;
        fa.W2p = w2t0;
        fa.b1 = g_b1[0]; fa.b2 = g_b2[0];
        fa.relu1 = 1; fa.relu2 = 1;
        fa.chain = 2;
        fgemm_kernel<<<dim3(GX, 1), 512, 0, stream>>>(fa, N, bA, 128);
    }

    // --- GIN layer 1: bA -> agg bB -> h2 = bC ---
    aggb_kernel<2, 0><<<AGG_GRID, 256, 0, stream>>>(bA, 128, rowptr, colI, invdeg, bB, 128, N, 64);
    {
        FArgs fa = {};
        fa.p[0] = {bB, w1t1, 128, 128};
        fa.np = 1;
        fa.W2p = w2t1;
        fa.b1 = g_b1[1]; fa.b2 = g_b2[1];
        fa.relu1 = 1; fa.relu2 = 1;
        fa.chain = 2;
        fgemm_kernel<<<dim3(GX, 1), 512, 0, stream>>>(fa, N, bC, 128);
    }

    // --- GIN layer 2 + gout (chain=3): bC -> agg bB -> gin = ginb ---
    aggb_kernel<2, 0><<<AGG_GRID, 256, 0, stream>>>(bC, 128, rowptr, colI, invdeg, bB, 128, N, 64);
    {
        FArgs fa = {};
        fa.p[0] = {bB, w1t2, 128, 128};
        fa.np = 1;
        fa.W2p = w2t2; fa.W3p = goutt;
        fa.b1 = g_b1[2]; fa.b2 = g_b2[2]; fa.b3 = gout_b;
        fa.relu1 = 1; fa.relu2 = 1; fa.relu3 = 0;
        fa.chain = 3;
        fgemm_kernel<<<dim3(GX, 1), 512, 0, stream>>>(fa, N, ginb, 128);
    }

    // mean1 gin-half: aggg = mean-agg(ginb) (128)
    aggb_kernel<2, 1><<<AGG_GRID, 256, 0, stream>>>(ginb, 128, rowptr, colI, invdeg, agggb, 128, N, 64);

    // s0 = relu(x@wl_top + gin@wl_bot + aggx@wr_top + aggg@wr_bot + b) (Nc=256)
    {
        FArgs fa = {};
        fa.p[0] = {xb, wltop, 64, 64};
        fa.p[1] = {ginb, wlbot, 128, 128};
        fa.p[2] = {aggxb, wrtop, 64, 64};
        fa.p[3] = {agggb, wrbot, 128, 128};
        fa.np = 4;
        fa.b1 = s0_b;
        fa.relu1 = 1;
        fa.chain = 1;
        fgemm_kernel<<<dim3(GX, 2), 512, 0, stream>>>(fa, N, s0b, 256);
    }

    // project-then-aggregate for the final layer
    zproj_kernel<<<(N + 3) / 4, 256, 0, stream>>>(s0b, s1_wl, s1_wr, zlb, zb, N);
    aggz_kernel<<<(N + TB - 1) / TB, TB, 0, stream>>>(zb, zlb, rowptr, colI, invdeg, s1_b, out, N);
}